// Round 5
// baseline (8005.431 us; speedup 1.0000x reference)
//
#include <hip/hip_runtime.h>
#include <math.h>

// ---- static problem config (matches reference) ----
namespace {
constexpr int N  = 102400;   // nodes
constexpr int E  = 819200;   // edges
constexpr int B_ = 16;       // graphs
constexpr int G  = 72;       // voxel cells per graph (8 x 9)
constexpr int GX = 8;
constexpr int NB = N / 256;  // 400 blocks over nodes
constexpr int EB = E / 256;  // 3200 blocks over edges
}

// ================= CSR build =================

__global__ __launch_bounds__(256) void count_kernel(const int* __restrict__ ei,
                                                    int* __restrict__ cnt) {
  int e = blockIdx.x * 256 + threadIdx.x;
  atomicAdd(&cnt[ei[E + e]], 1);
}

__global__ __launch_bounds__(256) void rcnt_kernel(const int* __restrict__ cnt,
                                                   float* __restrict__ rcnt) {
  int n = blockIdx.x * 256 + threadIdx.x;
  rcnt[n] = 1.0f / (float)max(cnt[n], 1);
}

// per-256-chunk sums of cnt
__global__ __launch_bounds__(256) void reduce_cnt(const int* __restrict__ cnt,
                                                  int* __restrict__ bsum) {
  __shared__ int s[256];
  int i = blockIdx.x * 256 + threadIdx.x;
  s[threadIdx.x] = cnt[i];
  __syncthreads();
  for (int st = 128; st > 0; st >>= 1) {
    if (threadIdx.x < st) s[threadIdx.x] += s[threadIdx.x + st];
    __syncthreads();
  }
  if (threadIdx.x == 0) bsum[blockIdx.x] = s[0];
}

// single-block exclusive scan of the NB block sums
__global__ __launch_bounds__(512) void scan_bsum(const int* __restrict__ bsum,
                                                 int* __restrict__ boff) {
  __shared__ int s[512];
  int i = threadIdx.x;
  int v = (i < NB) ? bsum[i] : 0;
  s[i] = v;
  __syncthreads();
  for (int st = 1; st < 512; st <<= 1) {
    int t = (i >= st) ? s[i - st] : 0;
    __syncthreads();
    s[i] += t;
    __syncthreads();
  }
  if (i < NB) boff[i] = s[i] - v;  // exclusive
}

// rowptr[n] = exclusive scan of cnt; cursor starts equal to rowptr
__global__ __launch_bounds__(256) void write_rowptr(const int* __restrict__ cnt,
                                                    const int* __restrict__ boff,
                                                    int* __restrict__ rowptr,
                                                    int* __restrict__ cursor) {
  __shared__ int s[256];
  int i = blockIdx.x * 256 + threadIdx.x;
  int v = cnt[i];
  s[threadIdx.x] = v;
  __syncthreads();
  for (int st = 1; st < 256; st <<= 1) {
    int t = (threadIdx.x >= st) ? s[threadIdx.x - st] : 0;
    __syncthreads();
    s[threadIdx.x] += t;
    __syncthreads();
  }
  int off = boff[blockIdx.x] + s[threadIdx.x] - v;  // exclusive
  rowptr[i] = off;
  cursor[i] = off;
  if (i == N - 1) rowptr[N] = off + v;
}

// scatter edge records (src + clamped pseudo-coords) into CSR order
__global__ __launch_bounds__(256) void edge_scatter(const int* __restrict__ ei,
                                                    const float* __restrict__ ea,
                                                    int* __restrict__ cursor,
                                                    float4* __restrict__ rec) {
  int e = blockIdx.x * 256 + threadIdx.x;
  int src = ei[e];
  int dst = ei[E + e];
  float u0 = fminf(fmaxf(ea[3 * e + 0], 0.f), 1.f);
  float u1 = fminf(fmaxf(ea[3 * e + 1], 0.f), 1.f);
  float u2 = fminf(fmaxf(ea[3 * e + 2], 0.f), 1.f);
  int slot = atomicAdd(&cursor[dst], 1);
  rec[slot] = make_float4(__int_as_float(src), u0, u1, u2);
}

// ============ bucket-sort nodes by degree (uniform wave trip counts) ============

__global__ __launch_bounds__(256) void hist_kernel(const int* __restrict__ cnt,
                                                   int* __restrict__ hist) {
  int n = blockIdx.x * 256 + threadIdx.x;
  atomicAdd(&hist[min(cnt[n], 63)], 1);
}

__global__ __launch_bounds__(64) void hist_scan(int* __restrict__ hist) {
  __shared__ int s[64];
  int i = threadIdx.x;
  int v = hist[i];
  s[i] = v;
  __syncthreads();
  for (int st = 1; st < 64; st <<= 1) {
    int t = (i >= st) ? s[i - st] : 0;
    __syncthreads();
    s[i] += t;
    __syncthreads();
  }
  hist[i] = s[i] - v;  // exclusive -> becomes cursor
}

__global__ __launch_bounds__(256) void order_kernel(const int* __restrict__ cnt,
                                                    int* __restrict__ hcur,
                                                    int* __restrict__ order) {
  int n = blockIdx.x * 256 + threadIdx.x;
  int pos = atomicAdd(&hcur[min(cnt[n], 63)], 1);
  order[pos] = n;
}

// ================= pooling helper =================
__device__ __forceinline__ void atomicMaxFloat(float* addr, float val) {
  if (val >= 0.f)
    atomicMax(reinterpret_cast<int*>(addr), __float_as_int(val));
  else
    atomicMin(reinterpret_cast<unsigned int*>(addr), __float_as_uint(val));
}

// ================= LDS-bridged factored spline conv =================
// out[n] = (1/deg) * sum_k ( sum_{e->n} b_k(e) * x_src(e) ) @ W[k]
// Phase 1 (wave-per-node): lane=(e_sub,k): e_sub lanes walk edges in parallel
//   (no serial gather chain), lane accumulates agg[CIN] for its k; reduce over
//   e_sub via reduce-and-split (masks 32/16/8, payload halves); vector LDS store.
// Phase 2 (block GEMM): thread=(node, co4): acc[4] over all (k,ci) from LDS agg
//   (bank-padded) x W float4 broadcast from L1 (co4-contiguous 128B lines).
// Epilogue: mean + ELU (+residual), float4 store or voxel-pool atomics.
template <int CIN, int COUT, bool RES, bool POOL>
__global__ __launch_bounds__(256) void node_conv_blk(
    const float* __restrict__ X, const float* __restrict__ W,
    const float4* __restrict__ rec, const int* __restrict__ rowptr,
    const int* __restrict__ order, const float* __restrict__ rcnt,
    const float* __restrict__ res, float* __restrict__ Y,
    const float* __restrict__ pos, const int* __restrict__ batch,
    float* __restrict__ pooled) {
  constexpr int TPN  = COUT / 4;       // phase-2 threads per node
  constexpr int NPB  = 256 / TPN;      // nodes per block
  constexpr int REPS = NPB / 4;        // phase-1 nodes per wave
  constexpr int KSTR = CIN + 4;        // k stride in LDS (dwords), 16B-aligned
  constexpr int NSTR = 8 * KSTR + 4;   // node stride (dwords), %32==4 -> no conflicts
  constexpr int SL   = (CIN >= 8) ? CIN / 8 : 1;  // final slice per lane

  __shared__ float sAgg[NPB * NSTR];

  const int tid  = threadIdx.x;
  const int wave = tid >> 6;
  const int lane = tid & 63;
  const int k    = lane & 7;   // owned spline kernel
  const int esub = lane >> 3;  // owned edge sub-stream

  // ---------------- phase 1 ----------------
  for (int rep = 0; rep < REPS; rep++) {
    const int sl = wave * REPS + rep;                 // wave-uniform
    const int n = order[blockIdx.x * NPB + sl];       // s_load
    const int beg = rowptr[n], end = rowptr[n + 1];

    float agg[CIN];
#pragma unroll
    for (int i = 0; i < CIN; i++) agg[i] = 0.f;

    for (int e = beg + esub; e < end; e += 8) {
      float4 r = rec[e];
      int src = __float_as_int(r.x);
      float f0 = (k & 1) ? r.y : 1.f - r.y;
      float f1 = (k & 2) ? r.z : 1.f - r.z;
      float f2 = (k & 4) ? r.w : 1.f - r.w;
      float bl = f0 * f1 * f2;

      if (CIN == 1) {
        agg[0] = fmaf(bl, X[src], agg[0]);
      } else {
        const float4* xp = reinterpret_cast<const float4*>(X + (size_t)src * CIN);
#pragma unroll
        for (int i = 0; i < CIN / 4; i++) {
          float4 v = xp[i];
          agg[4 * i + 0] = fmaf(bl, v.x, agg[4 * i + 0]);
          agg[4 * i + 1] = fmaf(bl, v.y, agg[4 * i + 1]);
          agg[4 * i + 2] = fmaf(bl, v.z, agg[4 * i + 2]);
          agg[4 * i + 3] = fmaf(bl, v.w, agg[4 * i + 3]);
        }
      }
    }

    if constexpr (CIN == 1) {
      float a = agg[0];
      a += __shfl_xor(a, 32, 64);
      a += __shfl_xor(a, 16, 64);
      a += __shfl_xor(a, 8, 64);
      if (esub == 0) sAgg[sl * NSTR + k * KSTR] = a;
    } else {
      // reduce-and-split over esub bits (5,4,3); lane ends with
      // agg[0..SL) = orig ci in [esub*SL, esub*SL+SL)
      {
        constexpr int H = CIN / 2;
        bool up = (lane & 32) != 0;
#pragma unroll
        for (int i = 0; i < H; i++) {
          float keep = up ? agg[i + H] : agg[i];
          float send = up ? agg[i] : agg[i + H];
          agg[i] = keep + __shfl_xor(send, 32, 64);
        }
      }
      {
        constexpr int H = CIN / 4;
        bool up = (lane & 16) != 0;
#pragma unroll
        for (int i = 0; i < H; i++) {
          float keep = up ? agg[i + H] : agg[i];
          float send = up ? agg[i] : agg[i + H];
          agg[i] = keep + __shfl_xor(send, 16, 64);
        }
      }
      {
        constexpr int H = CIN / 8;
        bool up = (lane & 8) != 0;
#pragma unroll
        for (int i = 0; i < H; i++) {
          float keep = up ? agg[i + H] : agg[i];
          float send = up ? agg[i] : agg[i + H];
          agg[i] = keep + __shfl_xor(send, 8, 64);
        }
      }
      const int base = sl * NSTR + k * KSTR + esub * SL;
      if constexpr (SL == 4) {
        *reinterpret_cast<float4*>(&sAgg[base]) =
            make_float4(agg[0], agg[1], agg[2], agg[3]);
      } else if constexpr (SL == 2) {
        *reinterpret_cast<float2*>(&sAgg[base]) = make_float2(agg[0], agg[1]);
      } else {
        sAgg[base] = agg[0];
      }
    }
  }
  __syncthreads();

  // ---------------- phase 2 ----------------
  const int node_l = tid / TPN;
  const int co4 = tid % TPN;
  const int n = order[blockIdx.x * NPB + node_l];

  float4 acc = make_float4(0.f, 0.f, 0.f, 0.f);
  const float4* W4 = reinterpret_cast<const float4*>(W);
  const float* arow = &sAgg[node_l * NSTR];

  if constexpr (CIN == 1) {
#pragma unroll
    for (int kk = 0; kk < 8; kk++) {
      float a = arow[kk * KSTR];
      float4 w = W4[kk * TPN + co4];
      acc.x = fmaf(a, w.x, acc.x);
      acc.y = fmaf(a, w.y, acc.y);
      acc.z = fmaf(a, w.z, acc.z);
      acc.w = fmaf(a, w.w, acc.w);
    }
  } else {
#pragma unroll
    for (int kk = 0; kk < 8; kk++) {
#pragma unroll
      for (int c = 0; c < CIN / 4; c++) {
        float4 a4 = *reinterpret_cast<const float4*>(&arow[kk * KSTR + 4 * c]);
        float4 w0 = W4[(kk * CIN + 4 * c + 0) * TPN + co4];
        float4 w1 = W4[(kk * CIN + 4 * c + 1) * TPN + co4];
        float4 w2 = W4[(kk * CIN + 4 * c + 2) * TPN + co4];
        float4 w3 = W4[(kk * CIN + 4 * c + 3) * TPN + co4];
        acc.x = fmaf(a4.x, w0.x, acc.x);
        acc.y = fmaf(a4.x, w0.y, acc.y);
        acc.z = fmaf(a4.x, w0.z, acc.z);
        acc.w = fmaf(a4.x, w0.w, acc.w);
        acc.x = fmaf(a4.y, w1.x, acc.x);
        acc.y = fmaf(a4.y, w1.y, acc.y);
        acc.z = fmaf(a4.y, w1.z, acc.z);
        acc.w = fmaf(a4.y, w1.w, acc.w);
        acc.x = fmaf(a4.z, w2.x, acc.x);
        acc.y = fmaf(a4.z, w2.y, acc.y);
        acc.z = fmaf(a4.z, w2.z, acc.z);
        acc.w = fmaf(a4.z, w2.w, acc.w);
        acc.x = fmaf(a4.w, w3.x, acc.x);
        acc.y = fmaf(a4.w, w3.y, acc.y);
        acc.z = fmaf(a4.w, w3.z, acc.z);
        acc.w = fmaf(a4.w, w3.w, acc.w);
      }
    }
  }

  const float rc = rcnt[n];
  float v[4] = {acc.x, acc.y, acc.z, acc.w};
#pragma unroll
  for (int i = 0; i < 4; i++) {
    float w = v[i] * rc;
    v[i] = w > 0.f ? w : expm1f(w);
  }
  if (RES) {
    float4 r4 = *reinterpret_cast<const float4*>(res + (size_t)n * COUT + co4 * 4);
    v[0] += r4.x;
    v[1] += r4.y;
    v[2] += r4.z;
    v[3] += r4.w;
  }

  if (POOL) {
    int cx = (int)floorf(pos[n * 3 + 0] / 16.0f);
    int cy = (int)floorf(pos[n * 3 + 1] / 12.0f);
    int cl = batch[n] * G + cy * GX + cx;
    float* pr = pooled + cl * 32 + co4 * 4;
#pragma unroll
    for (int i = 0; i < 4; i++) atomicMaxFloat(&pr[i], v[i]);
  } else {
    *reinterpret_cast<float4*>(Y + (size_t)n * COUT + co4 * 4) =
        make_float4(v[0], v[1], v[2], v[3]);
  }
}

// ================= final FC =================
__global__ __launch_bounds__(256) void fc_kernel(const float* __restrict__ pooled,
                                                 const float* __restrict__ fcw,
                                                 float* __restrict__ out) {
  int b = blockIdx.x >> 1;
  int o = blockIdx.x & 1;
  const float* pb = pooled + b * (G * 32);
  float s = 0.f;
  for (int i = threadIdx.x; i < G * 32; i += 256) {
    float v = pb[i];
    v = isfinite(v) ? v : 0.f;  // untouched cells (0xFF memset -> NaN) -> 0
    s += v * fcw[i * 2 + o];
  }
  __shared__ float red[256];
  red[threadIdx.x] = s;
  __syncthreads();
  for (int st = 128; st > 0; st >>= 1) {
    if (threadIdx.x < st) red[threadIdx.x] += red[threadIdx.x + st];
    __syncthreads();
  }
  if (threadIdx.x == 0) out[b * 2 + o] = red[0];
}

extern "C" void kernel_launch(void* const* d_in, const int* in_sizes, int n_in,
                              void* d_out, int out_size, void* d_ws, size_t ws_size,
                              hipStream_t stream) {
  const float* x     = (const float*)d_in[0];
  const float* pos   = (const float*)d_in[1];
  const float* ea    = (const float*)d_in[2];
  const int*   ei    = (const int*)d_in[3];
  const int*   batch = (const int*)d_in[4];
  const float* fcw   = (const float*)d_in[5];
  const float* w1    = (const float*)d_in[6];
  const float* w2    = (const float*)d_in[7];
  const float* w3    = (const float*)d_in[8];
  const float* w4    = (const float*)d_in[9];
  const float* w5    = (const float*)d_in[10];
  const float* w6    = (const float*)d_in[11];
  const float* w7    = (const float*)d_in[12];
  float* out = (float*)d_out;

  // ---- workspace layout (256B-aligned chunks) ----
  char* ws = (char*)d_ws;
  size_t off = 0;
  auto alloc = [&](size_t bytes) {
    size_t p = off;
    off += (bytes + 255) & ~(size_t)255;
    return ws + p;
  };
  float*  rcnt   = (float*)alloc((size_t)N * 4);
  int*    cnt    = (int*)alloc((size_t)N * 4);
  int*    rowptr = (int*)alloc((size_t)(N + 1) * 4);
  int*    cursor = (int*)alloc((size_t)N * 4);
  int*    bsum   = (int*)alloc(512 * 4);
  int*    boff   = (int*)alloc(512 * 4);
  int*    hist   = (int*)alloc(64 * 4);
  int*    order  = (int*)alloc((size_t)N * 4);
  float4* rec    = (float4*)alloc((size_t)E * 16);
  float*  bufA   = (float*)alloc((size_t)N * 32 * 4);
  float*  bufB   = (float*)alloc((size_t)N * 32 * 4);
  float*  bufC   = (float*)alloc((size_t)N * 32 * 4);
  float*  pooled = (float*)alloc((size_t)B_ * G * 32 * 4);

  // ---- CSR build ----
  hipMemsetAsync(cnt, 0, (size_t)N * 4, stream);
  count_kernel<<<EB, 256, 0, stream>>>(ei, cnt);
  rcnt_kernel<<<NB, 256, 0, stream>>>(cnt, rcnt);
  reduce_cnt<<<NB, 256, 0, stream>>>(cnt, bsum);
  scan_bsum<<<1, 512, 0, stream>>>(bsum, boff);
  write_rowptr<<<NB, 256, 0, stream>>>(cnt, boff, rowptr, cursor);
  edge_scatter<<<EB, 256, 0, stream>>>(ei, ea, cursor, rec);

  // ---- degree bucket sort ----
  hipMemsetAsync(hist, 0, 64 * 4, stream);
  hist_kernel<<<NB, 256, 0, stream>>>(cnt, hist);
  hist_scan<<<1, 64, 0, stream>>>(hist);
  order_kernel<<<NB, 256, 0, stream>>>(cnt, hist, order);

  // ---- pooled init (must precede conv7) ----
  hipMemsetAsync(pooled, 0xFF, (size_t)B_ * G * 32 * 4, stream);

  // ---- conv ladder (LDS-bridged factored) ----
  // conv1: 1->8    x -> A        NPB=128 -> 800 blocks
  node_conv_blk<1, 8, false, false><<<N / 128, 256, 0, stream>>>(
      x, w1, rec, rowptr, order, rcnt, nullptr, bufA, nullptr, nullptr, nullptr);
  // conv2: 8->16   A -> B   (B = h_sc1)   NPB=64 -> 1600 blocks
  node_conv_blk<8, 16, false, false><<<N / 64, 256, 0, stream>>>(
      bufA, w2, rec, rowptr, order, rcnt, nullptr, bufB, nullptr, nullptr, nullptr);
  // conv3: 16->16  B -> C
  node_conv_blk<16, 16, false, false><<<N / 64, 256, 0, stream>>>(
      bufB, w3, rec, rowptr, order, rcnt, nullptr, bufC, nullptr, nullptr, nullptr);
  // conv4: 16->16  C -> A, + residual B
  node_conv_blk<16, 16, true, false><<<N / 64, 256, 0, stream>>>(
      bufC, w4, rec, rowptr, order, rcnt, bufB, bufA, nullptr, nullptr, nullptr);
  // conv5: 16->32  A -> C   (C = h_sc2)   NPB=32 -> 3200 blocks
  node_conv_blk<16, 32, false, false><<<N / 32, 256, 0, stream>>>(
      bufA, w5, rec, rowptr, order, rcnt, nullptr, bufC, nullptr, nullptr, nullptr);
  // conv6: 32->32  C -> B
  node_conv_blk<32, 32, false, false><<<N / 32, 256, 0, stream>>>(
      bufC, w6, rec, rowptr, order, rcnt, nullptr, bufB, nullptr, nullptr, nullptr);
  // conv7: 32->32  B -> (pool), + residual C
  node_conv_blk<32, 32, true, true><<<N / 32, 256, 0, stream>>>(
      bufB, w7, rec, rowptr, order, rcnt, bufC, nullptr, pos, batch, pooled);

  // ---- FC ----
  fc_kernel<<<B_ * 2, 256, 0, stream>>>(pooled, fcw, out);
}

// Round 6
// 1777.680 us; speedup vs baseline: 4.5033x; 4.5033x over previous
//
#include <hip/hip_runtime.h>
#include <math.h>

// ---- static problem config (matches reference) ----
namespace {
constexpr int N  = 102400;   // nodes
constexpr int E  = 819200;   // edges
constexpr int B_ = 16;       // graphs
constexpr int G  = 72;       // voxel cells per graph (8 x 9)
constexpr int GX = 8;
constexpr int NB = N / 256;  // 400 blocks over nodes
constexpr int EB = E / 256;  // 3200 blocks over edges
}

// ================= CSR build =================

__global__ __launch_bounds__(256) void count_kernel(const int* __restrict__ ei,
                                                    int* __restrict__ cnt) {
  int e = blockIdx.x * 256 + threadIdx.x;
  atomicAdd(&cnt[ei[E + e]], 1);
}

__global__ __launch_bounds__(256) void rcnt_kernel(const int* __restrict__ cnt,
                                                   float* __restrict__ rcnt) {
  int n = blockIdx.x * 256 + threadIdx.x;
  rcnt[n] = 1.0f / (float)max(cnt[n], 1);
}

// per-256-chunk sums of cnt
__global__ __launch_bounds__(256) void reduce_cnt(const int* __restrict__ cnt,
                                                  int* __restrict__ bsum) {
  __shared__ int s[256];
  int i = blockIdx.x * 256 + threadIdx.x;
  s[threadIdx.x] = cnt[i];
  __syncthreads();
  for (int st = 128; st > 0; st >>= 1) {
    if (threadIdx.x < st) s[threadIdx.x] += s[threadIdx.x + st];
    __syncthreads();
  }
  if (threadIdx.x == 0) bsum[blockIdx.x] = s[0];
}

// single-block exclusive scan of the NB block sums
__global__ __launch_bounds__(512) void scan_bsum(const int* __restrict__ bsum,
                                                 int* __restrict__ boff) {
  __shared__ int s[512];
  int i = threadIdx.x;
  int v = (i < NB) ? bsum[i] : 0;
  s[i] = v;
  __syncthreads();
  for (int st = 1; st < 512; st <<= 1) {
    int t = (i >= st) ? s[i - st] : 0;
    __syncthreads();
    s[i] += t;
    __syncthreads();
  }
  if (i < NB) boff[i] = s[i] - v;  // exclusive
}

// rowptr[n] = exclusive scan of cnt; cursor starts equal to rowptr
__global__ __launch_bounds__(256) void write_rowptr(const int* __restrict__ cnt,
                                                    const int* __restrict__ boff,
                                                    int* __restrict__ rowptr,
                                                    int* __restrict__ cursor) {
  __shared__ int s[256];
  int i = blockIdx.x * 256 + threadIdx.x;
  int v = cnt[i];
  s[threadIdx.x] = v;
  __syncthreads();
  for (int st = 1; st < 256; st <<= 1) {
    int t = (threadIdx.x >= st) ? s[threadIdx.x - st] : 0;
    __syncthreads();
    s[threadIdx.x] += t;
    __syncthreads();
  }
  int off = boff[blockIdx.x] + s[threadIdx.x] - v;  // exclusive
  rowptr[i] = off;
  cursor[i] = off;
  if (i == N - 1) rowptr[N] = off + v;
}

// scatter edge records (src + clamped pseudo-coords) into CSR order
__global__ __launch_bounds__(256) void edge_scatter(const int* __restrict__ ei,
                                                    const float* __restrict__ ea,
                                                    int* __restrict__ cursor,
                                                    float4* __restrict__ rec) {
  int e = blockIdx.x * 256 + threadIdx.x;
  int src = ei[e];
  int dst = ei[E + e];
  float u0 = fminf(fmaxf(ea[3 * e + 0], 0.f), 1.f);
  float u1 = fminf(fmaxf(ea[3 * e + 1], 0.f), 1.f);
  float u2 = fminf(fmaxf(ea[3 * e + 2], 0.f), 1.f);
  int slot = atomicAdd(&cursor[dst], 1);
  rec[slot] = make_float4(__int_as_float(src), u0, u1, u2);
}

// ============ bucket-sort nodes by degree (uniform wave trip counts) ============

__global__ __launch_bounds__(256) void hist_kernel(const int* __restrict__ cnt,
                                                   int* __restrict__ hist) {
  int n = blockIdx.x * 256 + threadIdx.x;
  atomicAdd(&hist[min(cnt[n], 63)], 1);
}

__global__ __launch_bounds__(64) void hist_scan(int* __restrict__ hist) {
  __shared__ int s[64];
  int i = threadIdx.x;
  int v = hist[i];
  s[i] = v;
  __syncthreads();
  for (int st = 1; st < 64; st <<= 1) {
    int t = (i >= st) ? s[i - st] : 0;
    __syncthreads();
    s[i] += t;
    __syncthreads();
  }
  hist[i] = s[i] - v;  // exclusive -> becomes cursor
}

__global__ __launch_bounds__(256) void order_kernel(const int* __restrict__ cnt,
                                                    int* __restrict__ hcur,
                                                    int* __restrict__ order) {
  int n = blockIdx.x * 256 + threadIdx.x;
  int pos = atomicAdd(&hcur[min(cnt[n], 63)], 1);
  order[pos] = n;
}

// ================= pooling helper =================
__device__ __forceinline__ void atomicMaxFloat(float* addr, float val) {
  if (val >= 0.f)
    atomicMax(reinterpret_cast<int*>(addr), __float_as_int(val));
  else
    atomicMin(reinterpret_cast<unsigned int*>(addr), __float_as_uint(val));
}

// ================= LDS-bridged factored spline conv (lean-register) =================
// out[n] = (1/deg) * sum_k ( sum_{e->n} b_k(e) * x_src(e) ) @ W[k]
// Phase 1: lane = (node_sub, ci4, k). A node's 8*(CIN/4) lanes walk its edge
//   list together (rec broadcast, x row coalesced); each lane holds ONE float4
//   quad of agg (4 regs, no shuffles) and writes it to LDS.
//   #pragma unroll 1 on the rep loop prevents round-5's 8x-unroll spill.
// Phase 2: thread = (node, co4): acc[4] over (k,ci) from LDS (NSTR%32==4 ->
//   conflict-free b128 for 8-node groups) x W float4 broadcast from L1.
// Epilogue: mean + ELU (+residual), float4 store or voxel-pool atomics.
template <int CIN, int COUT, bool RES, bool POOL>
__global__ __launch_bounds__(256) void node_conv_v2(
    const float* __restrict__ X, const float* __restrict__ W,
    const float4* __restrict__ rec, const int* __restrict__ rowptr,
    const int* __restrict__ order, const float* __restrict__ rcnt,
    const float* __restrict__ res, float* __restrict__ Y,
    const float* __restrict__ pos, const int* __restrict__ batch,
    float* __restrict__ pooled) {
  constexpr int TPN  = COUT / 4;                  // phase-2 threads per node
  constexpr int NPB  = 256 / TPN;                 // nodes per block
  constexpr int LPN  = (CIN >= 8) ? 2 * CIN : 8;  // phase-1 lanes per node
  constexpr int NPW  = 64 / LPN;                  // phase-1 nodes per wave
  constexpr int REPS = NPB / (4 * NPW);           // phase-1 reps per wave
  constexpr int KSTR = (CIN >= 8) ? CIN + 4 : 1;  // k-stride (dwords), 16B-aligned
  constexpr int NSTR = 8 * KSTR + 4;              // node stride; %32==4 (or 12)
  constexpr int Q    = (CIN >= 8) ? CIN / 4 : 1;  // quads per k-row

  __shared__ float sAgg[NPB * NSTR];

  const int tid  = threadIdx.x;
  const int wave = tid >> 6;
  const int lane = tid & 63;

  // ---------------- phase 1 ----------------
  const int ns  = lane / LPN;           // node sub-slot within wave
  const int rem = lane & (LPN - 1);
  const int k   = rem & 7;              // owned spline kernel
  const int ci4 = (CIN >= 8) ? (rem >> 3) : 0;  // owned channel quad

#pragma unroll 1
  for (int rep = 0; rep < REPS; rep++) {
    const int sl = wave * (REPS * NPW) + rep * NPW + ns;
    const int n = order[blockIdx.x * NPB + sl];
    const int beg = rowptr[n], end = rowptr[n + 1];

    float a0 = 0.f, a1 = 0.f, a2 = 0.f, a3 = 0.f;
    float4 r = make_float4(0.f, 0.f, 0.f, 0.f);
    if (beg < end) r = rec[beg];

#pragma unroll 1
    for (int e = beg; e < end; e++) {
      float4 rn = r;
      if (e + 1 < end) rn = rec[e + 1];   // prefetch: breaks rec->x chain
      int src = __float_as_int(r.x);
      float f0 = (k & 1) ? r.y : 1.f - r.y;
      float f1 = (k & 2) ? r.z : 1.f - r.z;
      float f2 = (k & 4) ? r.w : 1.f - r.w;
      float bl = f0 * f1 * f2;

      if (CIN == 1) {
        a0 = fmaf(bl, X[src], a0);
      } else {
        float4 v =
            *reinterpret_cast<const float4*>(X + (size_t)src * CIN + ci4 * 4);
        a0 = fmaf(bl, v.x, a0);
        a1 = fmaf(bl, v.y, a1);
        a2 = fmaf(bl, v.z, a2);
        a3 = fmaf(bl, v.w, a3);
      }
      r = rn;
    }

    const int base = sl * NSTR + k * KSTR;
    if (CIN == 1) {
      sAgg[base] = a0;
    } else {
      *reinterpret_cast<float4*>(&sAgg[base + ci4 * 4]) =
          make_float4(a0, a1, a2, a3);
    }
  }
  __syncthreads();

  // ---------------- phase 2 ----------------
  const int node_l = tid / TPN;
  const int co4 = tid % TPN;
  const int n = order[blockIdx.x * NPB + node_l];

  float4 acc = make_float4(0.f, 0.f, 0.f, 0.f);
  const float4* W4 = reinterpret_cast<const float4*>(W);
  const float* arow = &sAgg[node_l * NSTR];

  if constexpr (CIN == 1) {
#pragma unroll
    for (int kk = 0; kk < 8; kk++) {
      float a = arow[kk * KSTR];
      float4 w = W4[kk * TPN + co4];
      acc.x = fmaf(a, w.x, acc.x);
      acc.y = fmaf(a, w.y, acc.y);
      acc.z = fmaf(a, w.z, acc.z);
      acc.w = fmaf(a, w.w, acc.w);
    }
  } else {
#pragma unroll 2
    for (int kk = 0; kk < 8; kk++) {
#pragma unroll
      for (int c = 0; c < Q; c++) {
        float4 a4 = *reinterpret_cast<const float4*>(&arow[kk * KSTR + 4 * c]);
        float4 w0 = W4[(kk * CIN + 4 * c + 0) * TPN + co4];
        float4 w1 = W4[(kk * CIN + 4 * c + 1) * TPN + co4];
        float4 w2 = W4[(kk * CIN + 4 * c + 2) * TPN + co4];
        float4 w3 = W4[(kk * CIN + 4 * c + 3) * TPN + co4];
        acc.x = fmaf(a4.x, w0.x, acc.x);
        acc.y = fmaf(a4.x, w0.y, acc.y);
        acc.z = fmaf(a4.x, w0.z, acc.z);
        acc.w = fmaf(a4.x, w0.w, acc.w);
        acc.x = fmaf(a4.y, w1.x, acc.x);
        acc.y = fmaf(a4.y, w1.y, acc.y);
        acc.z = fmaf(a4.y, w1.z, acc.z);
        acc.w = fmaf(a4.y, w1.w, acc.w);
        acc.x = fmaf(a4.z, w2.x, acc.x);
        acc.y = fmaf(a4.z, w2.y, acc.y);
        acc.z = fmaf(a4.z, w2.z, acc.z);
        acc.w = fmaf(a4.z, w2.w, acc.w);
        acc.x = fmaf(a4.w, w3.x, acc.x);
        acc.y = fmaf(a4.w, w3.y, acc.y);
        acc.z = fmaf(a4.w, w3.z, acc.z);
        acc.w = fmaf(a4.w, w3.w, acc.w);
      }
    }
  }

  const float rc = rcnt[n];
  float v[4] = {acc.x, acc.y, acc.z, acc.w};
#pragma unroll
  for (int i = 0; i < 4; i++) {
    float w = v[i] * rc;
    v[i] = w > 0.f ? w : expm1f(w);
  }
  if (RES) {
    float4 r4 = *reinterpret_cast<const float4*>(res + (size_t)n * COUT + co4 * 4);
    v[0] += r4.x;
    v[1] += r4.y;
    v[2] += r4.z;
    v[3] += r4.w;
  }

  if (POOL) {
    int cx = (int)floorf(pos[n * 3 + 0] / 16.0f);
    int cy = (int)floorf(pos[n * 3 + 1] / 12.0f);
    int cl = batch[n] * G + cy * GX + cx;
    float* pr = pooled + cl * 32 + co4 * 4;
#pragma unroll
    for (int i = 0; i < 4; i++) atomicMaxFloat(&pr[i], v[i]);
  } else {
    *reinterpret_cast<float4*>(Y + (size_t)n * COUT + co4 * 4) =
        make_float4(v[0], v[1], v[2], v[3]);
  }
}

// ================= final FC =================
__global__ __launch_bounds__(256) void fc_kernel(const float* __restrict__ pooled,
                                                 const float* __restrict__ fcw,
                                                 float* __restrict__ out) {
  int b = blockIdx.x >> 1;
  int o = blockIdx.x & 1;
  const float* pb = pooled + b * (G * 32);
  float s = 0.f;
  for (int i = threadIdx.x; i < G * 32; i += 256) {
    float v = pb[i];
    v = isfinite(v) ? v : 0.f;  // untouched cells (0xFF memset -> NaN) -> 0
    s += v * fcw[i * 2 + o];
  }
  __shared__ float red[256];
  red[threadIdx.x] = s;
  __syncthreads();
  for (int st = 128; st > 0; st >>= 1) {
    if (threadIdx.x < st) red[threadIdx.x] += red[threadIdx.x + st];
    __syncthreads();
  }
  if (threadIdx.x == 0) out[b * 2 + o] = red[0];
}

extern "C" void kernel_launch(void* const* d_in, const int* in_sizes, int n_in,
                              void* d_out, int out_size, void* d_ws, size_t ws_size,
                              hipStream_t stream) {
  const float* x     = (const float*)d_in[0];
  const float* pos   = (const float*)d_in[1];
  const float* ea    = (const float*)d_in[2];
  const int*   ei    = (const int*)d_in[3];
  const int*   batch = (const int*)d_in[4];
  const float* fcw   = (const float*)d_in[5];
  const float* w1    = (const float*)d_in[6];
  const float* w2    = (const float*)d_in[7];
  const float* w3    = (const float*)d_in[8];
  const float* w4    = (const float*)d_in[9];
  const float* w5    = (const float*)d_in[10];
  const float* w6    = (const float*)d_in[11];
  const float* w7    = (const float*)d_in[12];
  float* out = (float*)d_out;

  // ---- workspace layout (256B-aligned chunks) ----
  char* ws = (char*)d_ws;
  size_t off = 0;
  auto alloc = [&](size_t bytes) {
    size_t p = off;
    off += (bytes + 255) & ~(size_t)255;
    return ws + p;
  };
  float*  rcnt   = (float*)alloc((size_t)N * 4);
  int*    cnt    = (int*)alloc((size_t)N * 4);
  int*    rowptr = (int*)alloc((size_t)(N + 1) * 4);
  int*    cursor = (int*)alloc((size_t)N * 4);
  int*    bsum   = (int*)alloc(512 * 4);
  int*    boff   = (int*)alloc(512 * 4);
  int*    hist   = (int*)alloc(64 * 4);
  int*    order  = (int*)alloc((size_t)N * 4);
  float4* rec    = (float4*)alloc((size_t)E * 16);
  float*  bufA   = (float*)alloc((size_t)N * 32 * 4);
  float*  bufB   = (float*)alloc((size_t)N * 32 * 4);
  float*  bufC   = (float*)alloc((size_t)N * 32 * 4);
  float*  pooled = (float*)alloc((size_t)B_ * G * 32 * 4);

  // ---- CSR build ----
  hipMemsetAsync(cnt, 0, (size_t)N * 4, stream);
  count_kernel<<<EB, 256, 0, stream>>>(ei, cnt);
  rcnt_kernel<<<NB, 256, 0, stream>>>(cnt, rcnt);
  reduce_cnt<<<NB, 256, 0, stream>>>(cnt, bsum);
  scan_bsum<<<1, 512, 0, stream>>>(bsum, boff);
  write_rowptr<<<NB, 256, 0, stream>>>(cnt, boff, rowptr, cursor);
  edge_scatter<<<EB, 256, 0, stream>>>(ei, ea, cursor, rec);

  // ---- degree bucket sort ----
  hipMemsetAsync(hist, 0, 64 * 4, stream);
  hist_kernel<<<NB, 256, 0, stream>>>(cnt, hist);
  hist_scan<<<1, 64, 0, stream>>>(hist);
  order_kernel<<<NB, 256, 0, stream>>>(cnt, hist, order);

  // ---- pooled init (must precede conv7) ----
  hipMemsetAsync(pooled, 0xFF, (size_t)B_ * G * 32 * 4, stream);

  // ---- conv ladder (factored, lean-register LDS bridge) ----
  // conv1: 1->8    x -> A        NPB=128 -> 800 blocks
  node_conv_v2<1, 8, false, false><<<N / 128, 256, 0, stream>>>(
      x, w1, rec, rowptr, order, rcnt, nullptr, bufA, nullptr, nullptr, nullptr);
  // conv2: 8->16   A -> B   (B = h_sc1)   NPB=64 -> 1600 blocks
  node_conv_v2<8, 16, false, false><<<N / 64, 256, 0, stream>>>(
      bufA, w2, rec, rowptr, order, rcnt, nullptr, bufB, nullptr, nullptr, nullptr);
  // conv3: 16->16  B -> C
  node_conv_v2<16, 16, false, false><<<N / 64, 256, 0, stream>>>(
      bufB, w3, rec, rowptr, order, rcnt, nullptr, bufC, nullptr, nullptr, nullptr);
  // conv4: 16->16  C -> A, + residual B
  node_conv_v2<16, 16, true, false><<<N / 64, 256, 0, stream>>>(
      bufC, w4, rec, rowptr, order, rcnt, bufB, bufA, nullptr, nullptr, nullptr);
  // conv5: 16->32  A -> C   (C = h_sc2)   NPB=32 -> 3200 blocks
  node_conv_v2<16, 32, false, false><<<N / 32, 256, 0, stream>>>(
      bufA, w5, rec, rowptr, order, rcnt, nullptr, bufC, nullptr, nullptr, nullptr);
  // conv6: 32->32  C -> B
  node_conv_v2<32, 32, false, false><<<N / 32, 256, 0, stream>>>(
      bufC, w6, rec, rowptr, order, rcnt, nullptr, bufB, nullptr, nullptr, nullptr);
  // conv7: 32->32  B -> (pool), + residual C
  node_conv_v2<32, 32, true, true><<<N / 32, 256, 0, stream>>>(
      bufB, w7, rec, rowptr, order, rcnt, bufC, nullptr, pos, batch, pooled);

  // ---- FC ----
  fc_kernel<<<B_ * 2, 256, 0, stream>>>(pooled, fcw, out);
}

// Round 7
// 1077.484 us; speedup vs baseline: 7.4297x; 1.6498x over previous
//
#include <hip/hip_runtime.h>
#include <math.h>

// ---- static problem config (matches reference) ----
namespace {
constexpr int N  = 102400;   // nodes
constexpr int E  = 819200;   // edges
constexpr int B_ = 16;       // graphs
constexpr int G  = 72;       // voxel cells per graph (8 x 9)
constexpr int GX = 8;
constexpr int NB = N / 256;  // 400 blocks over nodes
constexpr int EB = E / 256;  // 3200 blocks over edges
}

// ================= CSR build =================

__global__ __launch_bounds__(256) void count_kernel(const int* __restrict__ ei,
                                                    int* __restrict__ cnt) {
  int e = blockIdx.x * 256 + threadIdx.x;
  atomicAdd(&cnt[ei[E + e]], 1);
}

__global__ __launch_bounds__(256) void rcnt_kernel(const int* __restrict__ cnt,
                                                   float* __restrict__ rcnt) {
  int n = blockIdx.x * 256 + threadIdx.x;
  rcnt[n] = 1.0f / (float)max(cnt[n], 1);
}

// per-256-chunk sums of cnt
__global__ __launch_bounds__(256) void reduce_cnt(const int* __restrict__ cnt,
                                                  int* __restrict__ bsum) {
  __shared__ int s[256];
  int i = blockIdx.x * 256 + threadIdx.x;
  s[threadIdx.x] = cnt[i];
  __syncthreads();
  for (int st = 128; st > 0; st >>= 1) {
    if (threadIdx.x < st) s[threadIdx.x] += s[threadIdx.x + st];
    __syncthreads();
  }
  if (threadIdx.x == 0) bsum[blockIdx.x] = s[0];
}

// single-block exclusive scan of the NB block sums
__global__ __launch_bounds__(512) void scan_bsum(const int* __restrict__ bsum,
                                                 int* __restrict__ boff) {
  __shared__ int s[512];
  int i = threadIdx.x;
  int v = (i < NB) ? bsum[i] : 0;
  s[i] = v;
  __syncthreads();
  for (int st = 1; st < 512; st <<= 1) {
    int t = (i >= st) ? s[i - st] : 0;
    __syncthreads();
    s[i] += t;
    __syncthreads();
  }
  if (i < NB) boff[i] = s[i] - v;  // exclusive
}

// rowptr[n] = exclusive scan of cnt; cursor starts equal to rowptr
__global__ __launch_bounds__(256) void write_rowptr(const int* __restrict__ cnt,
                                                    const int* __restrict__ boff,
                                                    int* __restrict__ rowptr,
                                                    int* __restrict__ cursor) {
  __shared__ int s[256];
  int i = blockIdx.x * 256 + threadIdx.x;
  int v = cnt[i];
  s[threadIdx.x] = v;
  __syncthreads();
  for (int st = 1; st < 256; st <<= 1) {
    int t = (threadIdx.x >= st) ? s[threadIdx.x - st] : 0;
    __syncthreads();
    s[threadIdx.x] += t;
    __syncthreads();
  }
  int off = boff[blockIdx.x] + s[threadIdx.x] - v;  // exclusive
  rowptr[i] = off;
  cursor[i] = off;
  if (i == N - 1) rowptr[N] = off + v;
}

// scatter edge records (src + clamped pseudo-coords) into CSR order
__global__ __launch_bounds__(256) void edge_scatter(const int* __restrict__ ei,
                                                    const float* __restrict__ ea,
                                                    int* __restrict__ cursor,
                                                    float4* __restrict__ rec) {
  int e = blockIdx.x * 256 + threadIdx.x;
  int src = ei[e];
  int dst = ei[E + e];
  float u0 = fminf(fmaxf(ea[3 * e + 0], 0.f), 1.f);
  float u1 = fminf(fmaxf(ea[3 * e + 1], 0.f), 1.f);
  float u2 = fminf(fmaxf(ea[3 * e + 2], 0.f), 1.f);
  int slot = atomicAdd(&cursor[dst], 1);
  rec[slot] = make_float4(__int_as_float(src), u0, u1, u2);
}

// ====== deterministic counting sort by degree (no global-atomic contention) ======
// Round 6 lesson: 102400 return-value atomicAdds onto ~20 hot addresses = 351 us.
// Replacement: per-block LDS histograms + one big scan + LDS-rank scatter.

// Pass A: per-block 64-bucket histogram, stored bucket-major bh[64][NB]
__global__ __launch_bounds__(256) void block_hist(const int* __restrict__ cnt,
                                                  int* __restrict__ bh) {
  __shared__ int h[64];
  if (threadIdx.x < 64) h[threadIdx.x] = 0;
  __syncthreads();
  int n = blockIdx.x * 256 + threadIdx.x;
  atomicAdd(&h[min(cnt[n], 63)], 1);  // LDS atomic, <=4-way avg contention
  __syncthreads();
  if (threadIdx.x < 64) bh[threadIdx.x * NB + blockIdx.x] = h[threadIdx.x];
}

// Pass B: exclusive scan of bh[64*NB] in ONE block (100 elements/thread)
__global__ __launch_bounds__(256) void scan_bh(int* __restrict__ bh) {
  constexpr int TOT = 64 * NB;     // 25600
  constexpr int CH  = TOT / 256;   // 100
  __shared__ int part[256];
  const int t = threadIdx.x;
  const int base = t * CH;
  int s = 0;
  for (int i = 0; i < CH; i++) s += bh[base + i];
  part[t] = s;
  __syncthreads();
  for (int st = 1; st < 256; st <<= 1) {
    int v = (t >= st) ? part[t - st] : 0;
    __syncthreads();
    part[t] += v;
    __syncthreads();
  }
  int run = part[t] - s;  // exclusive offset of this chunk
  for (int i = 0; i < CH; i++) {
    int v = bh[base + i];
    bh[base + i] = run;
    run += v;
  }
}

// Pass C: local rank via LDS atomic + global base from scanned bh
__global__ __launch_bounds__(256) void order_block(const int* __restrict__ cnt,
                                                   const int* __restrict__ bh,
                                                   int* __restrict__ order) {
  __shared__ int cur[64];
  if (threadIdx.x < 64) cur[threadIdx.x] = 0;
  __syncthreads();
  int n = blockIdx.x * 256 + threadIdx.x;
  int b = min(cnt[n], 63);
  int lr = atomicAdd(&cur[b], 1);  // LDS: local rank within (block,bucket)
  __syncthreads();
  if (threadIdx.x < 64) cur[threadIdx.x] = bh[threadIdx.x * NB + blockIdx.x];
  __syncthreads();
  order[cur[b] + lr] = n;
}

// ================= pooling helper =================
__device__ __forceinline__ void atomicMaxFloat(float* addr, float val) {
  if (val >= 0.f)
    atomicMax(reinterpret_cast<int*>(addr), __float_as_int(val));
  else
    atomicMin(reinterpret_cast<unsigned int*>(addr), __float_as_uint(val));
}

// ================= LDS-bridged factored spline conv (lean-register) =================
// out[n] = (1/deg) * sum_k ( sum_{e->n} b_k(e) * x_src(e) ) @ W[k]
// Phase 1: lane = (node_sub, ci4, k). A node's 8*(CIN/4) lanes walk its edge
//   list together (rec broadcast, x row coalesced); each lane holds ONE float4
//   quad of agg (4 regs, no shuffles) and writes it to LDS.
//   #pragma unroll 1 on the rep loop prevents round-5's 8x-unroll spill.
// Phase 2: thread = (node, co4): acc[4] over (k,ci) from LDS (NSTR%32==4 ->
//   conflict-free b128 for 8-node groups) x W float4 broadcast from L1.
// Epilogue: mean + ELU (+residual), float4 store or voxel-pool atomics.
template <int CIN, int COUT, bool RES, bool POOL>
__global__ __launch_bounds__(256) void node_conv_v2(
    const float* __restrict__ X, const float* __restrict__ W,
    const float4* __restrict__ rec, const int* __restrict__ rowptr,
    const int* __restrict__ order, const float* __restrict__ rcnt,
    const float* __restrict__ res, float* __restrict__ Y,
    const float* __restrict__ pos, const int* __restrict__ batch,
    float* __restrict__ pooled) {
  constexpr int TPN  = COUT / 4;                  // phase-2 threads per node
  constexpr int NPB  = 256 / TPN;                 // nodes per block
  constexpr int LPN  = (CIN >= 8) ? 2 * CIN : 8;  // phase-1 lanes per node
  constexpr int NPW  = 64 / LPN;                  // phase-1 nodes per wave
  constexpr int REPS = NPB / (4 * NPW);           // phase-1 reps per wave
  constexpr int KSTR = (CIN >= 8) ? CIN + 4 : 1;  // k-stride (dwords), 16B-aligned
  constexpr int NSTR = 8 * KSTR + 4;              // node stride; %32==4 (or 12)
  constexpr int Q    = (CIN >= 8) ? CIN / 4 : 1;  // quads per k-row

  __shared__ float sAgg[NPB * NSTR];

  const int tid  = threadIdx.x;
  const int wave = tid >> 6;
  const int lane = tid & 63;

  // ---------------- phase 1 ----------------
  const int ns  = lane / LPN;           // node sub-slot within wave
  const int rem = lane & (LPN - 1);
  const int k   = rem & 7;              // owned spline kernel
  const int ci4 = (CIN >= 8) ? (rem >> 3) : 0;  // owned channel quad

#pragma unroll 1
  for (int rep = 0; rep < REPS; rep++) {
    const int sl = wave * (REPS * NPW) + rep * NPW + ns;
    const int n = order[blockIdx.x * NPB + sl];
    const int beg = rowptr[n], end = rowptr[n + 1];

    float a0 = 0.f, a1 = 0.f, a2 = 0.f, a3 = 0.f;
    float4 r = make_float4(0.f, 0.f, 0.f, 0.f);
    if (beg < end) r = rec[beg];

#pragma unroll 1
    for (int e = beg; e < end; e++) {
      float4 rn = r;
      if (e + 1 < end) rn = rec[e + 1];   // prefetch: breaks rec->x chain
      int src = __float_as_int(r.x);
      float f0 = (k & 1) ? r.y : 1.f - r.y;
      float f1 = (k & 2) ? r.z : 1.f - r.z;
      float f2 = (k & 4) ? r.w : 1.f - r.w;
      float bl = f0 * f1 * f2;

      if (CIN == 1) {
        a0 = fmaf(bl, X[src], a0);
      } else {
        float4 v =
            *reinterpret_cast<const float4*>(X + (size_t)src * CIN + ci4 * 4);
        a0 = fmaf(bl, v.x, a0);
        a1 = fmaf(bl, v.y, a1);
        a2 = fmaf(bl, v.z, a2);
        a3 = fmaf(bl, v.w, a3);
      }
      r = rn;
    }

    const int base = sl * NSTR + k * KSTR;
    if (CIN == 1) {
      sAgg[base] = a0;
    } else {
      *reinterpret_cast<float4*>(&sAgg[base + ci4 * 4]) =
          make_float4(a0, a1, a2, a3);
    }
  }
  __syncthreads();

  // ---------------- phase 2 ----------------
  const int node_l = tid / TPN;
  const int co4 = tid % TPN;
  const int n = order[blockIdx.x * NPB + node_l];

  float4 acc = make_float4(0.f, 0.f, 0.f, 0.f);
  const float4* W4 = reinterpret_cast<const float4*>(W);
  const float* arow = &sAgg[node_l * NSTR];

  if constexpr (CIN == 1) {
#pragma unroll
    for (int kk = 0; kk < 8; kk++) {
      float a = arow[kk * KSTR];
      float4 w = W4[kk * TPN + co4];
      acc.x = fmaf(a, w.x, acc.x);
      acc.y = fmaf(a, w.y, acc.y);
      acc.z = fmaf(a, w.z, acc.z);
      acc.w = fmaf(a, w.w, acc.w);
    }
  } else {
#pragma unroll 2
    for (int kk = 0; kk < 8; kk++) {
#pragma unroll
      for (int c = 0; c < Q; c++) {
        float4 a4 = *reinterpret_cast<const float4*>(&arow[kk * KSTR + 4 * c]);
        float4 w0 = W4[(kk * CIN + 4 * c + 0) * TPN + co4];
        float4 w1 = W4[(kk * CIN + 4 * c + 1) * TPN + co4];
        float4 w2 = W4[(kk * CIN + 4 * c + 2) * TPN + co4];
        float4 w3 = W4[(kk * CIN + 4 * c + 3) * TPN + co4];
        acc.x = fmaf(a4.x, w0.x, acc.x);
        acc.y = fmaf(a4.x, w0.y, acc.y);
        acc.z = fmaf(a4.x, w0.z, acc.z);
        acc.w = fmaf(a4.x, w0.w, acc.w);
        acc.x = fmaf(a4.y, w1.x, acc.x);
        acc.y = fmaf(a4.y, w1.y, acc.y);
        acc.z = fmaf(a4.y, w1.z, acc.z);
        acc.w = fmaf(a4.y, w1.w, acc.w);
        acc.x = fmaf(a4.z, w2.x, acc.x);
        acc.y = fmaf(a4.z, w2.y, acc.y);
        acc.z = fmaf(a4.z, w2.z, acc.z);
        acc.w = fmaf(a4.z, w2.w, acc.w);
        acc.x = fmaf(a4.w, w3.x, acc.x);
        acc.y = fmaf(a4.w, w3.y, acc.y);
        acc.z = fmaf(a4.w, w3.z, acc.z);
        acc.w = fmaf(a4.w, w3.w, acc.w);
      }
    }
  }

  const float rc = rcnt[n];
  float v[4] = {acc.x, acc.y, acc.z, acc.w};
#pragma unroll
  for (int i = 0; i < 4; i++) {
    float w = v[i] * rc;
    v[i] = w > 0.f ? w : expm1f(w);
  }
  if (RES) {
    float4 r4 = *reinterpret_cast<const float4*>(res + (size_t)n * COUT + co4 * 4);
    v[0] += r4.x;
    v[1] += r4.y;
    v[2] += r4.z;
    v[3] += r4.w;
  }

  if (POOL) {
    int cx = (int)floorf(pos[n * 3 + 0] / 16.0f);
    int cy = (int)floorf(pos[n * 3 + 1] / 12.0f);
    int cl = batch[n] * G + cy * GX + cx;
    float* pr = pooled + cl * 32 + co4 * 4;
#pragma unroll
    for (int i = 0; i < 4; i++) atomicMaxFloat(&pr[i], v[i]);
  } else {
    *reinterpret_cast<float4*>(Y + (size_t)n * COUT + co4 * 4) =
        make_float4(v[0], v[1], v[2], v[3]);
  }
}

// ================= final FC =================
__global__ __launch_bounds__(256) void fc_kernel(const float* __restrict__ pooled,
                                                 const float* __restrict__ fcw,
                                                 float* __restrict__ out) {
  int b = blockIdx.x >> 1;
  int o = blockIdx.x & 1;
  const float* pb = pooled + b * (G * 32);
  float s = 0.f;
  for (int i = threadIdx.x; i < G * 32; i += 256) {
    float v = pb[i];
    v = isfinite(v) ? v : 0.f;  // untouched cells (0xFF memset -> NaN) -> 0
    s += v * fcw[i * 2 + o];
  }
  __shared__ float red[256];
  red[threadIdx.x] = s;
  __syncthreads();
  for (int st = 128; st > 0; st >>= 1) {
    if (threadIdx.x < st) red[threadIdx.x] += red[threadIdx.x + st];
    __syncthreads();
  }
  if (threadIdx.x == 0) out[b * 2 + o] = red[0];
}

extern "C" void kernel_launch(void* const* d_in, const int* in_sizes, int n_in,
                              void* d_out, int out_size, void* d_ws, size_t ws_size,
                              hipStream_t stream) {
  const float* x     = (const float*)d_in[0];
  const float* pos   = (const float*)d_in[1];
  const float* ea    = (const float*)d_in[2];
  const int*   ei    = (const int*)d_in[3];
  const int*   batch = (const int*)d_in[4];
  const float* fcw   = (const float*)d_in[5];
  const float* w1    = (const float*)d_in[6];
  const float* w2    = (const float*)d_in[7];
  const float* w3    = (const float*)d_in[8];
  const float* w4    = (const float*)d_in[9];
  const float* w5    = (const float*)d_in[10];
  const float* w6    = (const float*)d_in[11];
  const float* w7    = (const float*)d_in[12];
  float* out = (float*)d_out;

  // ---- workspace layout (256B-aligned chunks) ----
  char* ws = (char*)d_ws;
  size_t off = 0;
  auto alloc = [&](size_t bytes) {
    size_t p = off;
    off += (bytes + 255) & ~(size_t)255;
    return ws + p;
  };
  float*  rcnt   = (float*)alloc((size_t)N * 4);
  int*    cnt    = (int*)alloc((size_t)N * 4);
  int*    rowptr = (int*)alloc((size_t)(N + 1) * 4);
  int*    cursor = (int*)alloc((size_t)N * 4);
  int*    bsum   = (int*)alloc(512 * 4);
  int*    boff   = (int*)alloc(512 * 4);
  int*    bh     = (int*)alloc((size_t)64 * NB * 4);  // counting-sort histograms
  int*    order  = (int*)alloc((size_t)N * 4);
  float4* rec    = (float4*)alloc((size_t)E * 16);
  float*  bufA   = (float*)alloc((size_t)N * 32 * 4);
  float*  bufB   = (float*)alloc((size_t)N * 32 * 4);
  float*  bufC   = (float*)alloc((size_t)N * 32 * 4);
  float*  pooled = (float*)alloc((size_t)B_ * G * 32 * 4);

  // ---- CSR build ----
  hipMemsetAsync(cnt, 0, (size_t)N * 4, stream);
  count_kernel<<<EB, 256, 0, stream>>>(ei, cnt);
  rcnt_kernel<<<NB, 256, 0, stream>>>(cnt, rcnt);
  reduce_cnt<<<NB, 256, 0, stream>>>(cnt, bsum);
  scan_bsum<<<1, 512, 0, stream>>>(bsum, boff);
  write_rowptr<<<NB, 256, 0, stream>>>(cnt, boff, rowptr, cursor);
  edge_scatter<<<EB, 256, 0, stream>>>(ei, ea, cursor, rec);

  // ---- degree counting sort (deterministic, contention-free) ----
  block_hist<<<NB, 256, 0, stream>>>(cnt, bh);
  scan_bh<<<1, 256, 0, stream>>>(bh);
  order_block<<<NB, 256, 0, stream>>>(cnt, bh, order);

  // ---- pooled init (must precede conv7) ----
  hipMemsetAsync(pooled, 0xFF, (size_t)B_ * G * 32 * 4, stream);

  // ---- conv ladder (factored, lean-register LDS bridge) ----
  // conv1: 1->8    x -> A        NPB=128 -> 800 blocks
  node_conv_v2<1, 8, false, false><<<N / 128, 256, 0, stream>>>(
      x, w1, rec, rowptr, order, rcnt, nullptr, bufA, nullptr, nullptr, nullptr);
  // conv2: 8->16   A -> B   (B = h_sc1)   NPB=64 -> 1600 blocks
  node_conv_v2<8, 16, false, false><<<N / 64, 256, 0, stream>>>(
      bufA, w2, rec, rowptr, order, rcnt, nullptr, bufB, nullptr, nullptr, nullptr);
  // conv3: 16->16  B -> C
  node_conv_v2<16, 16, false, false><<<N / 64, 256, 0, stream>>>(
      bufB, w3, rec, rowptr, order, rcnt, nullptr, bufC, nullptr, nullptr, nullptr);
  // conv4: 16->16  C -> A, + residual B
  node_conv_v2<16, 16, true, false><<<N / 64, 256, 0, stream>>>(
      bufC, w4, rec, rowptr, order, rcnt, bufB, bufA, nullptr, nullptr, nullptr);
  // conv5: 16->32  A -> C   (C = h_sc2)   NPB=32 -> 3200 blocks
  node_conv_v2<16, 32, false, false><<<N / 32, 256, 0, stream>>>(
      bufA, w5, rec, rowptr, order, rcnt, nullptr, bufC, nullptr, nullptr, nullptr);
  // conv6: 32->32  C -> B
  node_conv_v2<32, 32, false, false><<<N / 32, 256, 0, stream>>>(
      bufC, w6, rec, rowptr, order, rcnt, nullptr, bufB, nullptr, nullptr, nullptr);
  // conv7: 32->32  B -> (pool), + residual C
  node_conv_v2<32, 32, true, true><<<N / 32, 256, 0, stream>>>(
      bufB, w7, rec, rowptr, order, rcnt, bufC, nullptr, pos, batch, pooled);

  // ---- FC ----
  fc_kernel<<<B_ * 2, 256, 0, stream>>>(pooled, fcw, out);
}

// Round 8
// 939.740 us; speedup vs baseline: 8.5188x; 1.1466x over previous
//
#include <hip/hip_runtime.h>
#include <math.h>

// ---- static problem config (matches reference) ----
namespace {
constexpr int N  = 102400;   // nodes
constexpr int E  = 819200;   // edges
constexpr int B_ = 16;       // graphs
constexpr int G  = 72;       // voxel cells per graph (8 x 9)
constexpr int GX = 8;
constexpr int NB = N / 256;  // 400 blocks over nodes
constexpr int EB = E / 256;  // 3200 blocks over edges
}

// ================= CSR build =================

__global__ __launch_bounds__(256) void count_kernel(const int* __restrict__ ei,
                                                    int* __restrict__ cnt) {
  int e = blockIdx.x * 256 + threadIdx.x;
  atomicAdd(&cnt[ei[E + e]], 1);
}

__global__ __launch_bounds__(256) void rcnt_kernel(const int* __restrict__ cnt,
                                                   float* __restrict__ rcnt) {
  int n = blockIdx.x * 256 + threadIdx.x;
  rcnt[n] = 1.0f / (float)max(cnt[n], 1);
}

// per-256-chunk sums of cnt
__global__ __launch_bounds__(256) void reduce_cnt(const int* __restrict__ cnt,
                                                  int* __restrict__ bsum) {
  __shared__ int s[256];
  int i = blockIdx.x * 256 + threadIdx.x;
  s[threadIdx.x] = cnt[i];
  __syncthreads();
  for (int st = 128; st > 0; st >>= 1) {
    if (threadIdx.x < st) s[threadIdx.x] += s[threadIdx.x + st];
    __syncthreads();
  }
  if (threadIdx.x == 0) bsum[blockIdx.x] = s[0];
}

// single-block exclusive scan of the NB block sums
__global__ __launch_bounds__(512) void scan_bsum(const int* __restrict__ bsum,
                                                 int* __restrict__ boff) {
  __shared__ int s[512];
  int i = threadIdx.x;
  int v = (i < NB) ? bsum[i] : 0;
  s[i] = v;
  __syncthreads();
  for (int st = 1; st < 512; st <<= 1) {
    int t = (i >= st) ? s[i - st] : 0;
    __syncthreads();
    s[i] += t;
    __syncthreads();
  }
  if (i < NB) boff[i] = s[i] - v;  // exclusive
}

// rowptr[n] = exclusive scan of cnt; cursor starts equal to rowptr
__global__ __launch_bounds__(256) void write_rowptr(const int* __restrict__ cnt,
                                                    const int* __restrict__ boff,
                                                    int* __restrict__ rowptr,
                                                    int* __restrict__ cursor) {
  __shared__ int s[256];
  int i = blockIdx.x * 256 + threadIdx.x;
  int v = cnt[i];
  s[threadIdx.x] = v;
  __syncthreads();
  for (int st = 1; st < 256; st <<= 1) {
    int t = (threadIdx.x >= st) ? s[threadIdx.x - st] : 0;
    __syncthreads();
    s[threadIdx.x] += t;
    __syncthreads();
  }
  int off = boff[blockIdx.x] + s[threadIdx.x] - v;  // exclusive
  rowptr[i] = off;
  cursor[i] = off;
  if (i == N - 1) rowptr[N] = off + v;
}

// scatter edge records (src + clamped pseudo-coords) into CSR order
__global__ __launch_bounds__(256) void edge_scatter(const int* __restrict__ ei,
                                                    const float* __restrict__ ea,
                                                    int* __restrict__ cursor,
                                                    float4* __restrict__ rec) {
  int e = blockIdx.x * 256 + threadIdx.x;
  int src = ei[e];
  int dst = ei[E + e];
  float u0 = fminf(fmaxf(ea[3 * e + 0], 0.f), 1.f);
  float u1 = fminf(fmaxf(ea[3 * e + 1], 0.f), 1.f);
  float u2 = fminf(fmaxf(ea[3 * e + 2], 0.f), 1.f);
  int slot = atomicAdd(&cursor[dst], 1);
  rec[slot] = make_float4(__int_as_float(src), u0, u1, u2);
}

// ====== deterministic counting sort by degree (no global-atomic contention) ======

// Pass A: per-block 64-bucket histogram, stored bucket-major bh[64][NB]
__global__ __launch_bounds__(256) void block_hist(const int* __restrict__ cnt,
                                                  int* __restrict__ bh) {
  __shared__ int h[64];
  if (threadIdx.x < 64) h[threadIdx.x] = 0;
  __syncthreads();
  int n = blockIdx.x * 256 + threadIdx.x;
  atomicAdd(&h[min(cnt[n], 63)], 1);  // LDS atomic, <=4-way avg contention
  __syncthreads();
  if (threadIdx.x < 64) bh[threadIdx.x * NB + blockIdx.x] = h[threadIdx.x];
}

// Pass B: exclusive scan of bh[64*NB] in ONE block (100 elements/thread)
__global__ __launch_bounds__(256) void scan_bh(int* __restrict__ bh) {
  constexpr int TOT = 64 * NB;     // 25600
  constexpr int CH  = TOT / 256;   // 100
  __shared__ int part[256];
  const int t = threadIdx.x;
  const int base = t * CH;
  int s = 0;
  for (int i = 0; i < CH; i++) s += bh[base + i];
  part[t] = s;
  __syncthreads();
  for (int st = 1; st < 256; st <<= 1) {
    int v = (t >= st) ? part[t - st] : 0;
    __syncthreads();
    part[t] += v;
    __syncthreads();
  }
  int run = part[t] - s;  // exclusive offset of this chunk
  for (int i = 0; i < CH; i++) {
    int v = bh[base + i];
    bh[base + i] = run;
    run += v;
  }
}

// Pass C: local rank via LDS atomic + global base from scanned bh
__global__ __launch_bounds__(256) void order_block(const int* __restrict__ cnt,
                                                   const int* __restrict__ bh,
                                                   int* __restrict__ order) {
  __shared__ int cur[64];
  if (threadIdx.x < 64) cur[threadIdx.x] = 0;
  __syncthreads();
  int n = blockIdx.x * 256 + threadIdx.x;
  int b = min(cnt[n], 63);
  int lr = atomicAdd(&cur[b], 1);  // LDS: local rank within (block,bucket)
  __syncthreads();
  if (threadIdx.x < 64) cur[threadIdx.x] = bh[threadIdx.x * NB + blockIdx.x];
  __syncthreads();
  order[cur[b] + lr] = n;
}

// ================= pooling helper =================
__device__ __forceinline__ void atomicMaxFloat(float* addr, float val) {
  if (val >= 0.f)
    atomicMax(reinterpret_cast<int*>(addr), __float_as_int(val));
  else
    atomicMin(reinterpret_cast<unsigned int*>(addr), __float_as_uint(val));
}

// ================= LDS-bridged factored spline conv (v3) =================
// out[n] = (1/deg) * sum_k ( sum_{e->n} b_k(e) * x_src(e) ) @ W[k]
//
// Phase 1, CIN>=16 (edge-parallel): lane=(esub,k), one node per wave per rep.
//   Each lane handles edges beg+esub(+8..): 1 rec load (contiguous across
//   esub) -> CIN/4 INDEPENDENT float4 x loads -> CIN FMAs into agg[CIN].
//   Dependent-chain depth ~2 loads per rep (was 8 serial gathers in v2).
//   3-stage reduce-and-split over esub bits (masks 8,16,32) leaves each lane
//   a CIN/8 slice at channel offset bitrev3(esub)*CIN/8 -> vector LDS write.
//   Rep loop is unroll-1 (round-5 spill lesson).
// Phase 1, CIN in {1,8}: v2 mapping (node_sub, ci4, k) — short chains already.
// Phase 2: thread=(node, co4): acc[4] over (k,ci) from LDS (NSTR%32==4 ->
//   conflict-free b128) x W float4 broadcast from L1.
template <int CIN, int COUT, bool RES, bool POOL>
__global__ __launch_bounds__(256) void node_conv_v3(
    const float* __restrict__ X, const float* __restrict__ W,
    const float4* __restrict__ rec, const int* __restrict__ rowptr,
    const int* __restrict__ order, const float* __restrict__ rcnt,
    const float* __restrict__ res, float* __restrict__ Y,
    const float* __restrict__ pos, const int* __restrict__ batch,
    float* __restrict__ pooled) {
  constexpr int TPN  = COUT / 4;                  // phase-2 threads per node
  constexpr int NPB  = 256 / TPN;                 // nodes per block
  constexpr int KSTR = (CIN >= 8) ? CIN + 4 : 1;  // k-stride (dwords), 16B-aligned
  constexpr int NSTR = 8 * KSTR + 4;              // node stride; %32==4 (or 12)
  constexpr int Q    = (CIN >= 8) ? CIN / 4 : 1;  // quads per k-row

  __shared__ float sAgg[NPB * NSTR];

  const int tid  = threadIdx.x;
  const int wave = tid >> 6;
  const int lane = tid & 63;

  // ---------------- phase 1 ----------------
  if constexpr (CIN >= 16) {
    // edge-parallel: one node per wave per rep; lane = (esub, k)
    constexpr int REPS = NPB / 4;
    const int esub = lane >> 3;
    const int k    = lane & 7;
    // channel offset of my final slice: bit-reversed esub
    const int start = ((lane >> 3) & 1) * (CIN / 2) +
                      ((lane >> 4) & 1) * (CIN / 4) +
                      ((lane >> 5) & 1) * (CIN / 8);

#pragma unroll 1
    for (int rep = 0; rep < REPS; rep++) {
      const int sl = wave * REPS + rep;
      const int n = order[blockIdx.x * NPB + sl];
      const int beg = rowptr[n], end = rowptr[n + 1];

      float agg[CIN];
#pragma unroll
      for (int i = 0; i < CIN; i++) agg[i] = 0.f;

#pragma unroll 1
      for (int e = beg + esub; e < end; e += 8) {
        float4 r = rec[e];  // 8 contiguous recs across esub lanes
        int src = __float_as_int(r.x);
        float f0 = (k & 1) ? r.y : 1.f - r.y;
        float f1 = (k & 2) ? r.z : 1.f - r.z;
        float f2 = (k & 4) ? r.w : 1.f - r.w;
        float bl = f0 * f1 * f2;
        const float4* xp =
            reinterpret_cast<const float4*>(X + (size_t)src * CIN);
#pragma unroll
        for (int q = 0; q < CIN / 4; q++) {
          float4 v = xp[q];  // independent loads -> MLP, no serial chain
          agg[4 * q + 0] = fmaf(bl, v.x, agg[4 * q + 0]);
          agg[4 * q + 1] = fmaf(bl, v.y, agg[4 * q + 1]);
          agg[4 * q + 2] = fmaf(bl, v.z, agg[4 * q + 2]);
          agg[4 * q + 3] = fmaf(bl, v.w, agg[4 * q + 3]);
        }
      }

      // reduce-and-split over esub bits: masks 8,16,32; payload halves
      {
        constexpr int H = CIN / 2;
        bool up = (lane & 8) != 0;
#pragma unroll
        for (int i = 0; i < H; i++) {
          float keep = up ? agg[i + H] : agg[i];
          float send = up ? agg[i] : agg[i + H];
          agg[i] = keep + __shfl_xor(send, 8, 64);
        }
      }
      {
        constexpr int H = CIN / 4;
        bool up = (lane & 16) != 0;
#pragma unroll
        for (int i = 0; i < H; i++) {
          float keep = up ? agg[i + H] : agg[i];
          float send = up ? agg[i] : agg[i + H];
          agg[i] = keep + __shfl_xor(send, 16, 64);
        }
      }
      {
        constexpr int H = CIN / 8;
        bool up = (lane & 32) != 0;
#pragma unroll
        for (int i = 0; i < H; i++) {
          float keep = up ? agg[i + H] : agg[i];
          float send = up ? agg[i] : agg[i + H];
          agg[i] = keep + __shfl_xor(send, 32, 64);
        }
      }

      const int base = sl * NSTR + k * KSTR + start;
      if constexpr (CIN == 32) {
        *reinterpret_cast<float4*>(&sAgg[base]) =
            make_float4(agg[0], agg[1], agg[2], agg[3]);
      } else {  // CIN == 16
        *reinterpret_cast<float2*>(&sAgg[base]) = make_float2(agg[0], agg[1]);
      }
    }
  } else {
    // v2 mapping for CIN in {1,8}: lane = (node_sub, ci4, k)
    constexpr int LPN  = (CIN >= 8) ? 2 * CIN : 8;
    constexpr int NPW  = 64 / LPN;
    constexpr int REPS = NPB / (4 * NPW);
    const int ns  = lane / LPN;
    const int rem = lane & (LPN - 1);
    const int k   = rem & 7;
    const int ci4 = (CIN >= 8) ? (rem >> 3) : 0;

#pragma unroll 1
    for (int rep = 0; rep < REPS; rep++) {
      const int sl = wave * (REPS * NPW) + rep * NPW + ns;
      const int n = order[blockIdx.x * NPB + sl];
      const int beg = rowptr[n], end = rowptr[n + 1];

      float a0 = 0.f, a1 = 0.f, a2 = 0.f, a3 = 0.f;
      float4 r = make_float4(0.f, 0.f, 0.f, 0.f);
      if (beg < end) r = rec[beg];

#pragma unroll 1
      for (int e = beg; e < end; e++) {
        float4 rn = r;
        if (e + 1 < end) rn = rec[e + 1];  // prefetch: breaks rec->x chain
        int src = __float_as_int(r.x);
        float f0 = (k & 1) ? r.y : 1.f - r.y;
        float f1 = (k & 2) ? r.z : 1.f - r.z;
        float f2 = (k & 4) ? r.w : 1.f - r.w;
        float bl = f0 * f1 * f2;

        if (CIN == 1) {
          a0 = fmaf(bl, X[src], a0);
        } else {
          float4 v =
              *reinterpret_cast<const float4*>(X + (size_t)src * CIN + ci4 * 4);
          a0 = fmaf(bl, v.x, a0);
          a1 = fmaf(bl, v.y, a1);
          a2 = fmaf(bl, v.z, a2);
          a3 = fmaf(bl, v.w, a3);
        }
        r = rn;
      }

      const int base = sl * NSTR + k * KSTR;
      if (CIN == 1) {
        sAgg[base] = a0;
      } else {
        *reinterpret_cast<float4*>(&sAgg[base + ci4 * 4]) =
            make_float4(a0, a1, a2, a3);
      }
    }
  }
  __syncthreads();

  // ---------------- phase 2 ----------------
  const int node_l = tid / TPN;
  const int co4 = tid % TPN;
  const int n = order[blockIdx.x * NPB + node_l];

  float4 acc = make_float4(0.f, 0.f, 0.f, 0.f);
  const float4* W4 = reinterpret_cast<const float4*>(W);
  const float* arow = &sAgg[node_l * NSTR];

  if constexpr (CIN == 1) {
#pragma unroll
    for (int kk = 0; kk < 8; kk++) {
      float a = arow[kk * KSTR];
      float4 w = W4[kk * TPN + co4];
      acc.x = fmaf(a, w.x, acc.x);
      acc.y = fmaf(a, w.y, acc.y);
      acc.z = fmaf(a, w.z, acc.z);
      acc.w = fmaf(a, w.w, acc.w);
    }
  } else {
#pragma unroll 2
    for (int kk = 0; kk < 8; kk++) {
#pragma unroll
      for (int c = 0; c < Q; c++) {
        float4 a4 = *reinterpret_cast<const float4*>(&arow[kk * KSTR + 4 * c]);
        float4 w0 = W4[(kk * CIN + 4 * c + 0) * TPN + co4];
        float4 w1 = W4[(kk * CIN + 4 * c + 1) * TPN + co4];
        float4 w2 = W4[(kk * CIN + 4 * c + 2) * TPN + co4];
        float4 w3 = W4[(kk * CIN + 4 * c + 3) * TPN + co4];
        acc.x = fmaf(a4.x, w0.x, acc.x);
        acc.y = fmaf(a4.x, w0.y, acc.y);
        acc.z = fmaf(a4.x, w0.z, acc.z);
        acc.w = fmaf(a4.x, w0.w, acc.w);
        acc.x = fmaf(a4.y, w1.x, acc.x);
        acc.y = fmaf(a4.y, w1.y, acc.y);
        acc.z = fmaf(a4.y, w1.z, acc.z);
        acc.w = fmaf(a4.y, w1.w, acc.w);
        acc.x = fmaf(a4.z, w2.x, acc.x);
        acc.y = fmaf(a4.z, w2.y, acc.y);
        acc.z = fmaf(a4.z, w2.z, acc.z);
        acc.w = fmaf(a4.z, w2.w, acc.w);
        acc.x = fmaf(a4.w, w3.x, acc.x);
        acc.y = fmaf(a4.w, w3.y, acc.y);
        acc.z = fmaf(a4.w, w3.z, acc.z);
        acc.w = fmaf(a4.w, w3.w, acc.w);
      }
    }
  }

  const float rc = rcnt[n];
  float v[4] = {acc.x, acc.y, acc.z, acc.w};
#pragma unroll
  for (int i = 0; i < 4; i++) {
    float w = v[i] * rc;
    v[i] = w > 0.f ? w : expm1f(w);
  }
  if (RES) {
    float4 r4 = *reinterpret_cast<const float4*>(res + (size_t)n * COUT + co4 * 4);
    v[0] += r4.x;
    v[1] += r4.y;
    v[2] += r4.z;
    v[3] += r4.w;
  }

  if (POOL) {
    int cx = (int)floorf(pos[n * 3 + 0] / 16.0f);
    int cy = (int)floorf(pos[n * 3 + 1] / 12.0f);
    int cl = batch[n] * G + cy * GX + cx;
    float* pr = pooled + cl * 32 + co4 * 4;
#pragma unroll
    for (int i = 0; i < 4; i++) atomicMaxFloat(&pr[i], v[i]);
  } else {
    *reinterpret_cast<float4*>(Y + (size_t)n * COUT + co4 * 4) =
        make_float4(v[0], v[1], v[2], v[3]);
  }
}

// ================= final FC =================
__global__ __launch_bounds__(256) void fc_kernel(const float* __restrict__ pooled,
                                                 const float* __restrict__ fcw,
                                                 float* __restrict__ out) {
  int b = blockIdx.x >> 1;
  int o = blockIdx.x & 1;
  const float* pb = pooled + b * (G * 32);
  float s = 0.f;
  for (int i = threadIdx.x; i < G * 32; i += 256) {
    float v = pb[i];
    v = isfinite(v) ? v : 0.f;  // untouched cells (0xFF memset -> NaN) -> 0
    s += v * fcw[i * 2 + o];
  }
  __shared__ float red[256];
  red[threadIdx.x] = s;
  __syncthreads();
  for (int st = 128; st > 0; st >>= 1) {
    if (threadIdx.x < st) red[threadIdx.x] += red[threadIdx.x + st];
    __syncthreads();
  }
  if (threadIdx.x == 0) out[b * 2 + o] = red[0];
}

extern "C" void kernel_launch(void* const* d_in, const int* in_sizes, int n_in,
                              void* d_out, int out_size, void* d_ws, size_t ws_size,
                              hipStream_t stream) {
  const float* x     = (const float*)d_in[0];
  const float* pos   = (const float*)d_in[1];
  const float* ea    = (const float*)d_in[2];
  const int*   ei    = (const int*)d_in[3];
  const int*   batch = (const int*)d_in[4];
  const float* fcw   = (const float*)d_in[5];
  const float* w1    = (const float*)d_in[6];
  const float* w2    = (const float*)d_in[7];
  const float* w3    = (const float*)d_in[8];
  const float* w4    = (const float*)d_in[9];
  const float* w5    = (const float*)d_in[10];
  const float* w6    = (const float*)d_in[11];
  const float* w7    = (const float*)d_in[12];
  float* out = (float*)d_out;

  // ---- workspace layout (256B-aligned chunks) ----
  char* ws = (char*)d_ws;
  size_t off = 0;
  auto alloc = [&](size_t bytes) {
    size_t p = off;
    off += (bytes + 255) & ~(size_t)255;
    return ws + p;
  };
  float*  rcnt   = (float*)alloc((size_t)N * 4);
  int*    cnt    = (int*)alloc((size_t)N * 4);
  int*    rowptr = (int*)alloc((size_t)(N + 1) * 4);
  int*    cursor = (int*)alloc((size_t)N * 4);
  int*    bsum   = (int*)alloc(512 * 4);
  int*    boff   = (int*)alloc(512 * 4);
  int*    bh     = (int*)alloc((size_t)64 * NB * 4);  // counting-sort histograms
  int*    order  = (int*)alloc((size_t)N * 4);
  float4* rec    = (float4*)alloc((size_t)E * 16);
  float*  bufA   = (float*)alloc((size_t)N * 32 * 4);
  float*  bufB   = (float*)alloc((size_t)N * 32 * 4);
  float*  bufC   = (float*)alloc((size_t)N * 32 * 4);
  float*  pooled = (float*)alloc((size_t)B_ * G * 32 * 4);

  // ---- CSR build ----
  hipMemsetAsync(cnt, 0, (size_t)N * 4, stream);
  count_kernel<<<EB, 256, 0, stream>>>(ei, cnt);
  rcnt_kernel<<<NB, 256, 0, stream>>>(cnt, rcnt);
  reduce_cnt<<<NB, 256, 0, stream>>>(cnt, bsum);
  scan_bsum<<<1, 512, 0, stream>>>(bsum, boff);
  write_rowptr<<<NB, 256, 0, stream>>>(cnt, boff, rowptr, cursor);
  edge_scatter<<<EB, 256, 0, stream>>>(ei, ea, cursor, rec);

  // ---- degree counting sort (deterministic, contention-free) ----
  block_hist<<<NB, 256, 0, stream>>>(cnt, bh);
  scan_bh<<<1, 256, 0, stream>>>(bh);
  order_block<<<NB, 256, 0, stream>>>(cnt, bh, order);

  // ---- pooled init (must precede conv7) ----
  hipMemsetAsync(pooled, 0xFF, (size_t)B_ * G * 32 * 4, stream);

  // ---- conv ladder (factored, edge-parallel phase 1 for CIN>=16) ----
  // conv1: 1->8    x -> A        NPB=128 -> 800 blocks
  node_conv_v3<1, 8, false, false><<<N / 128, 256, 0, stream>>>(
      x, w1, rec, rowptr, order, rcnt, nullptr, bufA, nullptr, nullptr, nullptr);
  // conv2: 8->16   A -> B   (B = h_sc1)   NPB=64 -> 1600 blocks
  node_conv_v3<8, 16, false, false><<<N / 64, 256, 0, stream>>>(
      bufA, w2, rec, rowptr, order, rcnt, nullptr, bufB, nullptr, nullptr, nullptr);
  // conv3: 16->16  B -> C
  node_conv_v3<16, 16, false, false><<<N / 64, 256, 0, stream>>>(
      bufB, w3, rec, rowptr, order, rcnt, nullptr, bufC, nullptr, nullptr, nullptr);
  // conv4: 16->16  C -> A, + residual B
  node_conv_v3<16, 16, true, false><<<N / 64, 256, 0, stream>>>(
      bufC, w4, rec, rowptr, order, rcnt, bufB, bufA, nullptr, nullptr, nullptr);
  // conv5: 16->32  A -> C   (C = h_sc2)   NPB=32 -> 3200 blocks
  node_conv_v3<16, 32, false, false><<<N / 32, 256, 0, stream>>>(
      bufA, w5, rec, rowptr, order, rcnt, nullptr, bufC, nullptr, nullptr, nullptr);
  // conv6: 32->32  C -> B
  node_conv_v3<32, 32, false, false><<<N / 32, 256, 0, stream>>>(
      bufC, w6, rec, rowptr, order, rcnt, nullptr, bufB, nullptr, nullptr, nullptr);
  // conv7: 32->32  B -> (pool), + residual C
  node_conv_v3<32, 32, true, true><<<N / 32, 256, 0, stream>>>(
      bufB, w7, rec, rowptr, order, rcnt, bufC, nullptr, pos, batch, pooled);

  // ---- FC ----
  fc_kernel<<<B_ * 2, 256, 0, stream>>>(pooled, fcw, out);
}

// Round 9
// 867.731 us; speedup vs baseline: 9.2257x; 1.0830x over previous
//
#include <hip/hip_runtime.h>
#include <math.h>

// ---- static problem config (matches reference) ----
namespace {
constexpr int N  = 102400;   // nodes
constexpr int E  = 819200;   // edges
constexpr int B_ = 16;       // graphs
constexpr int G  = 72;       // voxel cells per graph (8 x 9)
constexpr int GX = 8;
constexpr int NB = N / 256;  // 400 blocks over nodes
constexpr int EB = E / 256;  // 3200 blocks over edges
}

// ================= CSR build =================

__global__ __launch_bounds__(256) void count_kernel(const int* __restrict__ ei,
                                                    int* __restrict__ cnt) {
  int e = blockIdx.x * 256 + threadIdx.x;
  atomicAdd(&cnt[ei[E + e]], 1);
}

__global__ __launch_bounds__(256) void rcnt_kernel(const int* __restrict__ cnt,
                                                   float* __restrict__ rcnt) {
  int n = blockIdx.x * 256 + threadIdx.x;
  rcnt[n] = 1.0f / (float)max(cnt[n], 1);
}

// per-256-chunk sums of cnt
__global__ __launch_bounds__(256) void reduce_cnt(const int* __restrict__ cnt,
                                                  int* __restrict__ bsum) {
  __shared__ int s[256];
  int i = blockIdx.x * 256 + threadIdx.x;
  s[threadIdx.x] = cnt[i];
  __syncthreads();
  for (int st = 128; st > 0; st >>= 1) {
    if (threadIdx.x < st) s[threadIdx.x] += s[threadIdx.x + st];
    __syncthreads();
  }
  if (threadIdx.x == 0) bsum[blockIdx.x] = s[0];
}

// single-block exclusive scan of the NB block sums
__global__ __launch_bounds__(512) void scan_bsum(const int* __restrict__ bsum,
                                                 int* __restrict__ boff) {
  __shared__ int s[512];
  int i = threadIdx.x;
  int v = (i < NB) ? bsum[i] : 0;
  s[i] = v;
  __syncthreads();
  for (int st = 1; st < 512; st <<= 1) {
    int t = (i >= st) ? s[i - st] : 0;
    __syncthreads();
    s[i] += t;
    __syncthreads();
  }
  if (i < NB) boff[i] = s[i] - v;  // exclusive
}

// rowptr[n] = exclusive scan of cnt; cursor starts equal to rowptr
__global__ __launch_bounds__(256) void write_rowptr(const int* __restrict__ cnt,
                                                    const int* __restrict__ boff,
                                                    int* __restrict__ rowptr,
                                                    int* __restrict__ cursor) {
  __shared__ int s[256];
  int i = blockIdx.x * 256 + threadIdx.x;
  int v = cnt[i];
  s[threadIdx.x] = v;
  __syncthreads();
  for (int st = 1; st < 256; st <<= 1) {
    int t = (threadIdx.x >= st) ? s[threadIdx.x - st] : 0;
    __syncthreads();
    s[threadIdx.x] += t;
    __syncthreads();
  }
  int off = boff[blockIdx.x] + s[threadIdx.x] - v;  // exclusive
  rowptr[i] = off;
  cursor[i] = off;
  if (i == N - 1) rowptr[N] = off + v;
}

// scatter edge records (src + clamped pseudo-coords) into CSR order
__global__ __launch_bounds__(256) void edge_scatter(const int* __restrict__ ei,
                                                    const float* __restrict__ ea,
                                                    int* __restrict__ cursor,
                                                    float4* __restrict__ rec) {
  int e = blockIdx.x * 256 + threadIdx.x;
  int src = ei[e];
  int dst = ei[E + e];
  float u0 = fminf(fmaxf(ea[3 * e + 0], 0.f), 1.f);
  float u1 = fminf(fmaxf(ea[3 * e + 1], 0.f), 1.f);
  float u2 = fminf(fmaxf(ea[3 * e + 2], 0.f), 1.f);
  int slot = atomicAdd(&cursor[dst], 1);
  rec[slot] = make_float4(__int_as_float(src), u0, u1, u2);
}

// ====== deterministic counting sort by degree (no global-atomic contention) ======

// Pass A: per-block 64-bucket histogram, stored bucket-major bh[64][NB]
__global__ __launch_bounds__(256) void block_hist(const int* __restrict__ cnt,
                                                  int* __restrict__ bh) {
  __shared__ int h[64];
  if (threadIdx.x < 64) h[threadIdx.x] = 0;
  __syncthreads();
  int n = blockIdx.x * 256 + threadIdx.x;
  atomicAdd(&h[min(cnt[n], 63)], 1);  // LDS atomic, <=4-way avg contention
  __syncthreads();
  if (threadIdx.x < 64) bh[threadIdx.x * NB + blockIdx.x] = h[threadIdx.x];
}

// Pass B: exclusive scan of bh[64*NB] in ONE block (100 elements/thread)
__global__ __launch_bounds__(256) void scan_bh(int* __restrict__ bh) {
  constexpr int TOT = 64 * NB;     // 25600
  constexpr int CH  = TOT / 256;   // 100
  __shared__ int part[256];
  const int t = threadIdx.x;
  const int base = t * CH;
  int s = 0;
  for (int i = 0; i < CH; i++) s += bh[base + i];
  part[t] = s;
  __syncthreads();
  for (int st = 1; st < 256; st <<= 1) {
    int v = (t >= st) ? part[t - st] : 0;
    __syncthreads();
    part[t] += v;
    __syncthreads();
  }
  int run = part[t] - s;  // exclusive offset of this chunk
  for (int i = 0; i < CH; i++) {
    int v = bh[base + i];
    bh[base + i] = run;
    run += v;
  }
}

// Pass C: local rank via LDS atomic + global base from scanned bh.
// Also emits sdesc[slot] = (rowptr[n], rowptr[n+1]) so the conv kernels read
// ONE int2 per slot instead of chaining order[] -> rowptr[] (2 latencies saved).
__global__ __launch_bounds__(256) void order_block(const int* __restrict__ cnt,
                                                   const int* __restrict__ bh,
                                                   const int* __restrict__ rowptr,
                                                   int* __restrict__ order,
                                                   int2* __restrict__ sdesc) {
  __shared__ int cur[64];
  if (threadIdx.x < 64) cur[threadIdx.x] = 0;
  __syncthreads();
  int n = blockIdx.x * 256 + threadIdx.x;
  int b = min(cnt[n], 63);
  int lr = atomicAdd(&cur[b], 1);  // LDS: local rank within (block,bucket)
  int rb = rowptr[n], re = rowptr[n + 1];
  __syncthreads();
  if (threadIdx.x < 64) cur[threadIdx.x] = bh[threadIdx.x * NB + blockIdx.x];
  __syncthreads();
  int p = cur[b] + lr;
  order[p] = n;
  sdesc[p] = make_int2(rb, re);
}

// ================= pooling helper =================
__device__ __forceinline__ void atomicMaxFloat(float* addr, float val) {
  if (val >= 0.f)
    atomicMax(reinterpret_cast<int*>(addr), __float_as_int(val));
  else
    atomicMin(reinterpret_cast<unsigned int*>(addr), __float_as_uint(val));
}

// ================= LDS-bridged factored spline conv (v4) =================
// out[n] = (1/deg) * sum_k ( sum_{e->n} b_k(e) * x_src(e) ) @ W[k]
//
// Round-9 changes vs v3 (both phase-1 paths):
//  - sdesc[slot] replaces order[]->rowptr[] chain (4 -> 2 serial loads/rep)
//  - software pipeline with ROTATING SCALARS (no reg arrays -> no r5 spill):
//    while computing rep r, rep r+1's first rec and rep r+2's descriptor are
//    already in flight. Steady-state chain = x-load latency + compute only.
//  - phase-2 epilogue gathers (rcnt/res/pos/batch) issued BEFORE the GEMM.
template <int CIN, int COUT, bool RES, bool POOL>
__global__ __launch_bounds__(256) void node_conv_v4(
    const float* __restrict__ X, const float* __restrict__ W,
    const float4* __restrict__ rec, const int2* __restrict__ sdesc,
    const int* __restrict__ order, const float* __restrict__ rcnt,
    const float* __restrict__ res, float* __restrict__ Y,
    const float* __restrict__ pos, const int* __restrict__ batch,
    float* __restrict__ pooled) {
  constexpr int TPN  = COUT / 4;                  // phase-2 threads per node
  constexpr int NPB  = 256 / TPN;                 // nodes per block
  constexpr int KSTR = (CIN >= 8) ? CIN + 4 : 1;  // k-stride (dwords), 16B-aligned
  constexpr int NSTR = 8 * KSTR + 4;              // node stride; %32==4 (or 12)
  constexpr int Q    = (CIN >= 8) ? CIN / 4 : 1;  // quads per k-row

  __shared__ float sAgg[NPB * NSTR];

  const int tid  = threadIdx.x;
  const int wave = tid >> 6;
  const int lane = tid & 63;

  // ---------------- phase 1 ----------------
  if constexpr (CIN >= 16) {
    // edge-parallel: one node per wave per rep; lane = (esub, k)
    constexpr int REPS = NPB / 4;
    const int esub = lane >> 3;
    const int k    = lane & 7;
    // channel offset of my final slice: bit-reversed esub
    const int start = ((lane >> 3) & 1) * (CIN / 2) +
                      ((lane >> 4) & 1) * (CIN / 4) +
                      ((lane >> 5) & 1) * (CIN / 8);
    const int slotbase = blockIdx.x * NPB + wave * REPS;

    // pipeline primed: current descriptor + its first rec, next descriptor
    int2 seC = sdesc[slotbase];
    int2 seN = (REPS > 1) ? sdesc[slotbase + 1] : seC;
    int eC = seC.x + esub;
    bool vC = eC < seC.y;
    float4 rcC = make_float4(0.f, 0.f, 0.f, 0.f);
    if (vC) rcC = rec[eC];

#pragma unroll 1
    for (int rep = 0; rep < REPS; rep++) {
      // issue next rep's first rec + next-next descriptor (independent)
      int eN = seN.x + esub;
      bool vN = (rep + 1 < REPS) && (eN < seN.y);
      float4 rcN = make_float4(0.f, 0.f, 0.f, 0.f);
      if (vN) rcN = rec[eN];
      int2 seNN = (rep + 2 < REPS) ? sdesc[slotbase + rep + 2] : seN;

      float agg[CIN];
#pragma unroll
      for (int i = 0; i < CIN; i++) agg[i] = 0.f;

      if (vC) {
        float4 r = rcC;
        int e = eC + 8;
        while (true) {
          bool more = e < seC.y;
          float4 rn = r;
          if (more) rn = rec[e];  // overlap next rec with current compute
          int src = __float_as_int(r.x);
          float f0 = (k & 1) ? r.y : 1.f - r.y;
          float f1 = (k & 2) ? r.z : 1.f - r.z;
          float f2 = (k & 4) ? r.w : 1.f - r.w;
          float bl = f0 * f1 * f2;
          const float4* xp =
              reinterpret_cast<const float4*>(X + (size_t)src * CIN);
#pragma unroll
          for (int q = 0; q < CIN / 4; q++) {
            float4 v = xp[q];  // independent loads -> MLP
            agg[4 * q + 0] = fmaf(bl, v.x, agg[4 * q + 0]);
            agg[4 * q + 1] = fmaf(bl, v.y, agg[4 * q + 1]);
            agg[4 * q + 2] = fmaf(bl, v.z, agg[4 * q + 2]);
            agg[4 * q + 3] = fmaf(bl, v.w, agg[4 * q + 3]);
          }
          if (!more) break;
          r = rn;
          e += 8;
        }
      }

      // reduce-and-split over esub bits: masks 8,16,32; payload halves
      {
        constexpr int H = CIN / 2;
        bool up = (lane & 8) != 0;
#pragma unroll
        for (int i = 0; i < H; i++) {
          float keep = up ? agg[i + H] : agg[i];
          float send = up ? agg[i] : agg[i + H];
          agg[i] = keep + __shfl_xor(send, 8, 64);
        }
      }
      {
        constexpr int H = CIN / 4;
        bool up = (lane & 16) != 0;
#pragma unroll
        for (int i = 0; i < H; i++) {
          float keep = up ? agg[i + H] : agg[i];
          float send = up ? agg[i] : agg[i + H];
          agg[i] = keep + __shfl_xor(send, 16, 64);
        }
      }
      {
        constexpr int H = CIN / 8;
        bool up = (lane & 32) != 0;
#pragma unroll
        for (int i = 0; i < H; i++) {
          float keep = up ? agg[i + H] : agg[i];
          float send = up ? agg[i] : agg[i + H];
          agg[i] = keep + __shfl_xor(send, 32, 64);
        }
      }

      const int base = (wave * REPS + rep) * NSTR + k * KSTR + start;
      if constexpr (CIN == 32) {
        *reinterpret_cast<float4*>(&sAgg[base]) =
            make_float4(agg[0], agg[1], agg[2], agg[3]);
      } else {  // CIN == 16
        *reinterpret_cast<float2*>(&sAgg[base]) = make_float2(agg[0], agg[1]);
      }

      // rotate pipeline state
      seC = seN;
      seN = seNN;
      eC = eN;
      vC = vN;
      rcC = rcN;
    }
  } else {
    // CIN in {1,8}: lane = (node_sub, ci4, k); serial edge walk w/ prefetch
    constexpr int LPN  = (CIN >= 8) ? 2 * CIN : 8;
    constexpr int NPW  = 64 / LPN;
    constexpr int REPS = NPB / (4 * NPW);
    const int ns  = lane / LPN;
    const int rem = lane & (LPN - 1);
    const int k   = rem & 7;
    const int ci4 = (CIN >= 8) ? (rem >> 3) : 0;
    const int slotbase = blockIdx.x * NPB + wave * (REPS * NPW) + ns;

    int2 seC = sdesc[slotbase];
    int2 seN = (REPS > 1) ? sdesc[slotbase + NPW] : seC;
    float4 rcC = make_float4(0.f, 0.f, 0.f, 0.f);
    bool vC = seC.x < seC.y;
    if (vC) rcC = rec[seC.x];

#pragma unroll 1
    for (int rep = 0; rep < REPS; rep++) {
      bool vN = (rep + 1 < REPS) && (seN.x < seN.y);
      float4 rcN = make_float4(0.f, 0.f, 0.f, 0.f);
      if (vN) rcN = rec[seN.x];
      int2 seNN = (rep + 2 < REPS) ? sdesc[slotbase + (rep + 2) * NPW] : seN;

      float a0 = 0.f, a1 = 0.f, a2 = 0.f, a3 = 0.f;
      if (vC) {
        float4 r = rcC;
        int e = seC.x + 1;
        while (true) {
          bool more = e < seC.y;
          float4 rn = r;
          if (more) rn = rec[e];  // prefetch: breaks rec->x chain
          int src = __float_as_int(r.x);
          float f0 = (k & 1) ? r.y : 1.f - r.y;
          float f1 = (k & 2) ? r.z : 1.f - r.z;
          float f2 = (k & 4) ? r.w : 1.f - r.w;
          float bl = f0 * f1 * f2;
          if (CIN == 1) {
            a0 = fmaf(bl, X[src], a0);
          } else {
            float4 v = *reinterpret_cast<const float4*>(
                X + (size_t)src * CIN + ci4 * 4);
            a0 = fmaf(bl, v.x, a0);
            a1 = fmaf(bl, v.y, a1);
            a2 = fmaf(bl, v.z, a2);
            a3 = fmaf(bl, v.w, a3);
          }
          if (!more) break;
          r = rn;
          e++;
        }
      }

      const int sl = wave * (REPS * NPW) + rep * NPW + ns;
      const int base = sl * NSTR + k * KSTR;
      if (CIN == 1) {
        sAgg[base] = a0;
      } else {
        *reinterpret_cast<float4*>(&sAgg[base + ci4 * 4]) =
            make_float4(a0, a1, a2, a3);
      }

      seC = seN;
      seN = seNN;
      vC = vN;
      rcC = rcN;
    }
  }
  __syncthreads();

  // ---------------- phase 2 ----------------
  const int node_l = tid / TPN;
  const int co4 = tid % TPN;
  const int n = order[blockIdx.x * NPB + node_l];

  // epilogue gathers issued BEFORE the GEMM: their latency hides under FMAs
  const float rc = rcnt[n];
  float4 rres = make_float4(0.f, 0.f, 0.f, 0.f);
  if constexpr (RES)
    rres = *reinterpret_cast<const float4*>(res + (size_t)n * COUT + co4 * 4);
  float p0 = 0.f, p1 = 0.f;
  int bi = 0;
  if constexpr (POOL) {
    p0 = pos[n * 3 + 0];
    p1 = pos[n * 3 + 1];
    bi = batch[n];
  }

  float4 acc = make_float4(0.f, 0.f, 0.f, 0.f);
  const float4* W4 = reinterpret_cast<const float4*>(W);
  const float* arow = &sAgg[node_l * NSTR];

  if constexpr (CIN == 1) {
#pragma unroll
    for (int kk = 0; kk < 8; kk++) {
      float a = arow[kk * KSTR];
      float4 w = W4[kk * TPN + co4];
      acc.x = fmaf(a, w.x, acc.x);
      acc.y = fmaf(a, w.y, acc.y);
      acc.z = fmaf(a, w.z, acc.z);
      acc.w = fmaf(a, w.w, acc.w);
    }
  } else {
#pragma unroll 2
    for (int kk = 0; kk < 8; kk++) {
#pragma unroll
      for (int c = 0; c < Q; c++) {
        float4 a4 = *reinterpret_cast<const float4*>(&arow[kk * KSTR + 4 * c]);
        float4 w0 = W4[(kk * CIN + 4 * c + 0) * TPN + co4];
        float4 w1 = W4[(kk * CIN + 4 * c + 1) * TPN + co4];
        float4 w2 = W4[(kk * CIN + 4 * c + 2) * TPN + co4];
        float4 w3 = W4[(kk * CIN + 4 * c + 3) * TPN + co4];
        acc.x = fmaf(a4.x, w0.x, acc.x);
        acc.y = fmaf(a4.x, w0.y, acc.y);
        acc.z = fmaf(a4.x, w0.z, acc.z);
        acc.w = fmaf(a4.x, w0.w, acc.w);
        acc.x = fmaf(a4.y, w1.x, acc.x);
        acc.y = fmaf(a4.y, w1.y, acc.y);
        acc.z = fmaf(a4.y, w1.z, acc.z);
        acc.w = fmaf(a4.y, w1.w, acc.w);
        acc.x = fmaf(a4.z, w2.x, acc.x);
        acc.y = fmaf(a4.z, w2.y, acc.y);
        acc.z = fmaf(a4.z, w2.z, acc.z);
        acc.w = fmaf(a4.z, w2.w, acc.w);
        acc.x = fmaf(a4.w, w3.x, acc.x);
        acc.y = fmaf(a4.w, w3.y, acc.y);
        acc.z = fmaf(a4.w, w3.z, acc.z);
        acc.w = fmaf(a4.w, w3.w, acc.w);
      }
    }
  }

  float v[4] = {acc.x, acc.y, acc.z, acc.w};
#pragma unroll
  for (int i = 0; i < 4; i++) {
    float w = v[i] * rc;
    v[i] = w > 0.f ? w : expm1f(w);
  }
  if constexpr (RES) {
    v[0] += rres.x;
    v[1] += rres.y;
    v[2] += rres.z;
    v[3] += rres.w;
  }

  if constexpr (POOL) {
    int cx = (int)floorf(p0 / 16.0f);
    int cy = (int)floorf(p1 / 12.0f);
    int cl = bi * G + cy * GX + cx;
    float* pr = pooled + cl * 32 + co4 * 4;
#pragma unroll
    for (int i = 0; i < 4; i++) atomicMaxFloat(&pr[i], v[i]);
  } else {
    *reinterpret_cast<float4*>(Y + (size_t)n * COUT + co4 * 4) =
        make_float4(v[0], v[1], v[2], v[3]);
  }
}

// ================= final FC =================
__global__ __launch_bounds__(256) void fc_kernel(const float* __restrict__ pooled,
                                                 const float* __restrict__ fcw,
                                                 float* __restrict__ out) {
  int b = blockIdx.x >> 1;
  int o = blockIdx.x & 1;
  const float* pb = pooled + b * (G * 32);
  float s = 0.f;
  for (int i = threadIdx.x; i < G * 32; i += 256) {
    float v = pb[i];
    v = isfinite(v) ? v : 0.f;  // untouched cells (0xFF memset -> NaN) -> 0
    s += v * fcw[i * 2 + o];
  }
  __shared__ float red[256];
  red[threadIdx.x] = s;
  __syncthreads();
  for (int st = 128; st > 0; st >>= 1) {
    if (threadIdx.x < st) red[threadIdx.x] += red[threadIdx.x + st];
    __syncthreads();
  }
  if (threadIdx.x == 0) out[b * 2 + o] = red[0];
}

extern "C" void kernel_launch(void* const* d_in, const int* in_sizes, int n_in,
                              void* d_out, int out_size, void* d_ws, size_t ws_size,
                              hipStream_t stream) {
  const float* x     = (const float*)d_in[0];
  const float* pos   = (const float*)d_in[1];
  const float* ea    = (const float*)d_in[2];
  const int*   ei    = (const int*)d_in[3];
  const int*   batch = (const int*)d_in[4];
  const float* fcw   = (const float*)d_in[5];
  const float* w1    = (const float*)d_in[6];
  const float* w2    = (const float*)d_in[7];
  const float* w3    = (const float*)d_in[8];
  const float* w4    = (const float*)d_in[9];
  const float* w5    = (const float*)d_in[10];
  const float* w6    = (const float*)d_in[11];
  const float* w7    = (const float*)d_in[12];
  float* out = (float*)d_out;

  // ---- workspace layout (256B-aligned chunks) ----
  char* ws = (char*)d_ws;
  size_t off = 0;
  auto alloc = [&](size_t bytes) {
    size_t p = off;
    off += (bytes + 255) & ~(size_t)255;
    return ws + p;
  };
  float*  rcnt   = (float*)alloc((size_t)N * 4);
  int*    cnt    = (int*)alloc((size_t)N * 4);
  int*    rowptr = (int*)alloc((size_t)(N + 1) * 4);
  int*    cursor = (int*)alloc((size_t)N * 4);
  int*    bsum   = (int*)alloc(512 * 4);
  int*    boff   = (int*)alloc(512 * 4);
  int*    bh     = (int*)alloc((size_t)64 * NB * 4);  // counting-sort histograms
  int*    order  = (int*)alloc((size_t)N * 4);
  int2*   sdesc  = (int2*)alloc((size_t)N * 8);       // sorted (beg,end) descriptors
  float4* rec    = (float4*)alloc((size_t)E * 16);
  float*  bufA   = (float*)alloc((size_t)N * 32 * 4);
  float*  bufB   = (float*)alloc((size_t)N * 32 * 4);
  float*  bufC   = (float*)alloc((size_t)N * 32 * 4);
  float*  pooled = (float*)alloc((size_t)B_ * G * 32 * 4);

  // ---- CSR build ----
  hipMemsetAsync(cnt, 0, (size_t)N * 4, stream);
  count_kernel<<<EB, 256, 0, stream>>>(ei, cnt);
  rcnt_kernel<<<NB, 256, 0, stream>>>(cnt, rcnt);
  reduce_cnt<<<NB, 256, 0, stream>>>(cnt, bsum);
  scan_bsum<<<1, 512, 0, stream>>>(bsum, boff);
  write_rowptr<<<NB, 256, 0, stream>>>(cnt, boff, rowptr, cursor);
  edge_scatter<<<EB, 256, 0, stream>>>(ei, ea, cursor, rec);

  // ---- degree counting sort (deterministic, contention-free) ----
  block_hist<<<NB, 256, 0, stream>>>(cnt, bh);
  scan_bh<<<1, 256, 0, stream>>>(bh);
  order_block<<<NB, 256, 0, stream>>>(cnt, bh, rowptr, order, sdesc);

  // ---- pooled init (must precede conv7) ----
  hipMemsetAsync(pooled, 0xFF, (size_t)B_ * G * 32 * 4, stream);

  // ---- conv ladder (factored, pipelined phase 1) ----
  // conv1: 1->8    x -> A        NPB=128 -> 800 blocks
  node_conv_v4<1, 8, false, false><<<N / 128, 256, 0, stream>>>(
      x, w1, rec, sdesc, order, rcnt, nullptr, bufA, nullptr, nullptr, nullptr);
  // conv2: 8->16   A -> B   (B = h_sc1)   NPB=64 -> 1600 blocks
  node_conv_v4<8, 16, false, false><<<N / 64, 256, 0, stream>>>(
      bufA, w2, rec, sdesc, order, rcnt, nullptr, bufB, nullptr, nullptr, nullptr);
  // conv3: 16->16  B -> C
  node_conv_v4<16, 16, false, false><<<N / 64, 256, 0, stream>>>(
      bufB, w3, rec, sdesc, order, rcnt, nullptr, bufC, nullptr, nullptr, nullptr);
  // conv4: 16->16  C -> A, + residual B
  node_conv_v4<16, 16, true, false><<<N / 64, 256, 0, stream>>>(
      bufC, w4, rec, sdesc, order, rcnt, bufB, bufA, nullptr, nullptr, nullptr);
  // conv5: 16->32  A -> C   (C = h_sc2)   NPB=32 -> 3200 blocks
  node_conv_v4<16, 32, false, false><<<N / 32, 256, 0, stream>>>(
      bufA, w5, rec, sdesc, order, rcnt, nullptr, bufC, nullptr, nullptr, nullptr);
  // conv6: 32->32  C -> B
  node_conv_v4<32, 32, false, false><<<N / 32, 256, 0, stream>>>(
      bufC, w6, rec, sdesc, order, rcnt, nullptr, bufB, nullptr, nullptr, nullptr);
  // conv7: 32->32  B -> (pool), + residual C
  node_conv_v4<32, 32, true, true><<<N / 32, 256, 0, stream>>>(
      bufB, w7, rec, sdesc, order, rcnt, bufC, nullptr, pos, batch, pooled);

  // ---- FC ----
  fc_kernel<<<B_ * 2, 256, 0, stream>>>(pooled, fcw, out);
}

// Round 10
// 698.878 us; speedup vs baseline: 11.4547x; 1.2416x over previous
//
#include <hip/hip_runtime.h>
#include <math.h>

// ---- static problem config (matches reference) ----
namespace {
constexpr int N  = 102400;   // nodes
constexpr int E  = 819200;   // edges
constexpr int B_ = 16;       // graphs
constexpr int G  = 72;       // voxel cells per graph (8 x 9)
constexpr int GX = 8;
constexpr int NB = N / 256;  // 400 blocks over nodes
constexpr int EB = E / 256;  // 3200 blocks over edges
}

// ================= CSR build =================

__global__ __launch_bounds__(256) void count_kernel(const int* __restrict__ ei,
                                                    int* __restrict__ cnt) {
  int e = blockIdx.x * 256 + threadIdx.x;
  atomicAdd(&cnt[ei[E + e]], 1);
}

__global__ __launch_bounds__(256) void rcnt_kernel(const int* __restrict__ cnt,
                                                   float* __restrict__ rcnt) {
  int n = blockIdx.x * 256 + threadIdx.x;
  rcnt[n] = 1.0f / (float)max(cnt[n], 1);
}

// per-256-chunk sums of cnt
__global__ __launch_bounds__(256) void reduce_cnt(const int* __restrict__ cnt,
                                                  int* __restrict__ bsum) {
  __shared__ int s[256];
  int i = blockIdx.x * 256 + threadIdx.x;
  s[threadIdx.x] = cnt[i];
  __syncthreads();
  for (int st = 128; st > 0; st >>= 1) {
    if (threadIdx.x < st) s[threadIdx.x] += s[threadIdx.x + st];
    __syncthreads();
  }
  if (threadIdx.x == 0) bsum[blockIdx.x] = s[0];
}

// single-block exclusive scan of the NB block sums
__global__ __launch_bounds__(512) void scan_bsum(const int* __restrict__ bsum,
                                                 int* __restrict__ boff) {
  __shared__ int s[512];
  int i = threadIdx.x;
  int v = (i < NB) ? bsum[i] : 0;
  s[i] = v;
  __syncthreads();
  for (int st = 1; st < 512; st <<= 1) {
    int t = (i >= st) ? s[i - st] : 0;
    __syncthreads();
    s[i] += t;
    __syncthreads();
  }
  if (i < NB) boff[i] = s[i] - v;  // exclusive
}

// rowptr[n] = exclusive scan of cnt; cursor starts equal to rowptr
__global__ __launch_bounds__(256) void write_rowptr(const int* __restrict__ cnt,
                                                    const int* __restrict__ boff,
                                                    int* __restrict__ rowptr,
                                                    int* __restrict__ cursor) {
  __shared__ int s[256];
  int i = blockIdx.x * 256 + threadIdx.x;
  int v = cnt[i];
  s[threadIdx.x] = v;
  __syncthreads();
  for (int st = 1; st < 256; st <<= 1) {
    int t = (threadIdx.x >= st) ? s[threadIdx.x - st] : 0;
    __syncthreads();
    s[threadIdx.x] += t;
    __syncthreads();
  }
  int off = boff[blockIdx.x] + s[threadIdx.x] - v;  // exclusive
  rowptr[i] = off;
  cursor[i] = off;
  if (i == N - 1) rowptr[N] = off + v;
}

// scatter edge records (src + clamped pseudo-coords) into CSR order
__global__ __launch_bounds__(256) void edge_scatter(const int* __restrict__ ei,
                                                    const float* __restrict__ ea,
                                                    int* __restrict__ cursor,
                                                    float4* __restrict__ rec) {
  int e = blockIdx.x * 256 + threadIdx.x;
  int src = ei[e];
  int dst = ei[E + e];
  float u0 = fminf(fmaxf(ea[3 * e + 0], 0.f), 1.f);
  float u1 = fminf(fmaxf(ea[3 * e + 1], 0.f), 1.f);
  float u2 = fminf(fmaxf(ea[3 * e + 2], 0.f), 1.f);
  int slot = atomicAdd(&cursor[dst], 1);
  rec[slot] = make_float4(__int_as_float(src), u0, u1, u2);
}

// ====== deterministic counting sort by degree (no global-atomic contention) ======

// Pass A: per-block 64-bucket histogram, stored bucket-major bh[64][NB]
__global__ __launch_bounds__(256) void block_hist(const int* __restrict__ cnt,
                                                  int* __restrict__ bh) {
  __shared__ int h[64];
  if (threadIdx.x < 64) h[threadIdx.x] = 0;
  __syncthreads();
  int n = blockIdx.x * 256 + threadIdx.x;
  atomicAdd(&h[min(cnt[n], 63)], 1);  // LDS atomic
  __syncthreads();
  if (threadIdx.x < 64) bh[threadIdx.x * NB + blockIdx.x] = h[threadIdx.x];
}

// Pass B: exclusive scan of bh[64*NB] in ONE block (100 elements/thread)
__global__ __launch_bounds__(256) void scan_bh(int* __restrict__ bh) {
  constexpr int TOT = 64 * NB;     // 25600
  constexpr int CH  = TOT / 256;   // 100
  __shared__ int part[256];
  const int t = threadIdx.x;
  const int base = t * CH;
  int s = 0;
  for (int i = 0; i < CH; i++) s += bh[base + i];
  part[t] = s;
  __syncthreads();
  for (int st = 1; st < 256; st <<= 1) {
    int v = (t >= st) ? part[t - st] : 0;
    __syncthreads();
    part[t] += v;
    __syncthreads();
  }
  int run = part[t] - s;  // exclusive offset of this chunk
  for (int i = 0; i < CH; i++) {
    int v = bh[base + i];
    bh[base + i] = run;
    run += v;
  }
}

// Pass C: local rank via LDS atomic + global base; emits order + sdesc(beg,end)
__global__ __launch_bounds__(256) void order_block(const int* __restrict__ cnt,
                                                   const int* __restrict__ bh,
                                                   const int* __restrict__ rowptr,
                                                   int* __restrict__ order,
                                                   int2* __restrict__ sdesc) {
  __shared__ int cur[64];
  if (threadIdx.x < 64) cur[threadIdx.x] = 0;
  __syncthreads();
  int n = blockIdx.x * 256 + threadIdx.x;
  int b = min(cnt[n], 63);
  int lr = atomicAdd(&cur[b], 1);
  int rb = rowptr[n], re = rowptr[n + 1];
  __syncthreads();
  if (threadIdx.x < 64) cur[threadIdx.x] = bh[threadIdx.x * NB + blockIdx.x];
  __syncthreads();
  int p = cur[b] + lr;
  order[p] = n;
  sdesc[p] = make_int2(rb, re);
}

// ================= pooling helper =================
__device__ __forceinline__ void atomicMaxFloat(float* addr, float val) {
  if (val >= 0.f)
    atomicMax(reinterpret_cast<int*>(addr), __float_as_int(val));
  else
    atomicMin(reinterpret_cast<unsigned int*>(addr), __float_as_uint(val));
}

// ================= LDS-bridged factored spline conv (v5: transposed gather) ======
// out[n] = (1/deg) * sum_k ( sum_{e->n} b_k(e) * x_src(e) ) @ W[k]
//
// Phase 1 (CIN>=8, TRANSPOSED): lane = (ns, esub, ci4). Lane loads ONE float4
//   channel-quad of its edge-stream's x row -> x loads are a single fully
//   coalesced instruction per edge-group (was 8 scattered instrs in v4).
//   Lane accumulates all 8 k's: agg[8][4] (32 regs). Reduce-and-split over
//   esub bits (masks QN,2QN,4QN; payload 32->16->8->4) leaves lane one
//   (k*,ci4) quad -> one b128 LDS write, XOR-(node&7) block swizzle, 0 pad.
//   Pipeline: descs 3-ahead, rec pairs (covers deg<=16) 2-ahead, x pairs
//   1-ahead, rotating scalars only. Rep loop unroll-1 (r5 spill lesson).
// Phase 2: thread=(node,co4); reads swizzled LDS quads (conflict-free: co4
//   lanes broadcast, nodes hit distinct bank-quads via XOR) x W float4 L1
//   broadcast. Epilogue gathers hoisted to kernel TOP (hide under phase 1).
template <int CIN, int COUT, bool RES, bool POOL>
__global__ __launch_bounds__(256, 4) void node_conv_v5(
    const float* __restrict__ X, const float* __restrict__ W,
    const float4* __restrict__ rec, const int2* __restrict__ sdesc,
    const int* __restrict__ order, const float* __restrict__ rcnt,
    const float* __restrict__ res, float* __restrict__ Y,
    const float* __restrict__ pos, const int* __restrict__ batch,
    float* __restrict__ pooled) {
  constexpr int TPN  = COUT / 4;                    // phase-2 threads per node
  constexpr int NPB  = 256 / TPN;                   // nodes per block
  constexpr int ROWF = (CIN >= 8) ? 8 * CIN : 12;   // LDS floats per node row

  __shared__ float sAgg[NPB * ROWF];

  const int tid  = threadIdx.x;
  const int wave = tid >> 6;
  const int lane = tid & 63;

  // ---- phase-2 epilogue gathers hoisted to top: hide under phase 1 ----
  const int node_l = tid / TPN;
  const int co4 = tid % TPN;
  const int n2 = order[blockIdx.x * NPB + node_l];
  const float rc = rcnt[n2];
  float4 rres = make_float4(0.f, 0.f, 0.f, 0.f);
  if constexpr (RES)
    rres = *reinterpret_cast<const float4*>(res + (size_t)n2 * COUT + co4 * 4);
  float p0 = 0.f, p1 = 0.f;
  int bi = 0;
  if constexpr (POOL) {
    p0 = pos[n2 * 3 + 0];
    p1 = pos[n2 * 3 + 1];
    bi = batch[n2];
  }

  // ---------------- phase 1 ----------------
  if constexpr (CIN >= 8) {
    constexpr int QN   = CIN / 4;          // channel quads per row
    constexpr int LPN  = 8 * QN;           // lanes per node
    constexpr int NPW  = 64 / LPN;         // nodes per wave per rep
    constexpr int REPS = NPB / (4 * NPW);  // reps per wave

    const int ci4  = lane % QN;
    const int esub = (lane / QN) & 7;
    const int ns   = lane / LPN;
    const int kstar = ((lane / QN) & 1) * 4 + ((lane / (2 * QN)) & 1) * 2 +
                      ((lane / (4 * QN)) & 1);
    const int slot0 = wave * (REPS * NPW) + ns;  // local slot of rep 0

    auto loadDesc = [&](int rep) -> int2 {
      int r = min(rep, REPS - 1);
      return sdesc[blockIdx.x * NPB + slot0 + r * NPW];
    };
    auto loadRec = [&](int e) -> float4 { return rec[min(e, E - 1)]; };
    auto loadX = [&](const float4& r) -> float4 {
      int src = __float_as_int(r.x);
      return *(reinterpret_cast<const float4*>(X + (size_t)src * CIN) + ci4);
    };

    // pipeline prologue
    int2 d0 = loadDesc(0);
    int2 d1 = loadDesc(1);
    int2 d2 = loadDesc(2);
    float4 ra0 = loadRec(d0.x + esub), rb0 = loadRec(d0.x + esub + 8);
    float4 ra1 = loadRec(d1.x + esub), rb1 = loadRec(d1.x + esub + 8);
    float4 xa0 = loadX(ra0), xb0 = loadX(rb0);

#pragma unroll 1
    for (int rep = 0; rep < REPS; rep++) {
      // issue next-rep x pair (recs arrived one rep ago)
      float4 xa1 = loadX(ra1), xb1 = loadX(rb1);
      // issue rep+2 rec pair (desc arrived one rep ago)
      float4 ra2 = loadRec(d2.x + esub), rb2 = loadRec(d2.x + esub + 8);
      // issue rep+3 desc
      int2 d3 = loadDesc(rep + 3);

      float agg[32];
#pragma unroll
      for (int i = 0; i < 32; i++) agg[i] = 0.f;

      auto accum = [&](const float4& r, const float4& v, bool valid) {
        float uy = r.y, uz = r.z, uw = r.w;
        float py = 1.f - uy, pz = 1.f - uz, pw = 1.f - uw;
        float g = valid ? 1.f : 0.f;
        float t0 = py * pz * g, t1 = uy * pz * g;
        float t2 = py * uz * g, t3 = uy * uz * g;
        float b[8] = {t0 * pw, t1 * pw, t2 * pw, t3 * pw,
                      t0 * uw, t1 * uw, t2 * uw, t3 * uw};
#pragma unroll
        for (int k = 0; k < 8; k++) {
          agg[k * 4 + 0] = fmaf(b[k], v.x, agg[k * 4 + 0]);
          agg[k * 4 + 1] = fmaf(b[k], v.y, agg[k * 4 + 1]);
          agg[k * 4 + 2] = fmaf(b[k], v.z, agg[k * 4 + 2]);
          agg[k * 4 + 3] = fmaf(b[k], v.w, agg[k * 4 + 3]);
        }
      };

      accum(ra0, xa0, d0.x + esub < d0.y);
      accum(rb0, xb0, d0.x + esub + 8 < d0.y);
      // rare: deg > 16 (P ~ 0.2%), exposed-latency fallback
#pragma unroll 1
      for (int e = d0.x + esub + 16; e < d0.y; e += 8) {
        float4 rr = rec[e];
        float4 xx = loadX(rr);
        accum(rr, xx, true);
      }

      // reduce-and-split over esub bits; payload 32 -> 16 -> 8 -> 4
#pragma unroll
      for (int s = 0; s < 3; s++) {
        const int m = QN << s;
        const int H = 16 >> s;
        bool up = (lane & m) != 0;
#pragma unroll
        for (int i = 0; i < H; i++) {
          float keep = up ? agg[i + H] : agg[i];
          float send = up ? agg[i] : agg[i + H];
          agg[i] = keep + __shfl_xor(send, m, 64);
        }
      }

      const int sl = slot0 + rep * NPW;
      const int idx4 = (kstar * QN + ci4) ^ (sl & 7);  // block swizzle
      *reinterpret_cast<float4*>(&sAgg[sl * ROWF + idx4 * 4]) =
          make_float4(agg[0], agg[1], agg[2], agg[3]);

      // rotate pipeline
      d0 = d1; d1 = d2; d2 = d3;
      ra0 = ra1; rb0 = rb1; ra1 = ra2; rb1 = rb2;
      xa0 = xa1; xb0 = xb1;
    }
  } else {
    // CIN == 1: lane = (node_sub, k); serial edge walk with prefetch
    constexpr int LPN  = 8;
    constexpr int NPW  = 8;
    constexpr int REPS = NPB / (4 * NPW);
    const int ns = lane / LPN;
    const int k  = lane & 7;
    const int slotbase = blockIdx.x * NPB + wave * (REPS * NPW) + ns;

    int2 seC = sdesc[slotbase];
    int2 seN = (REPS > 1) ? sdesc[slotbase + NPW] : seC;
    float4 rcC = make_float4(0.f, 0.f, 0.f, 0.f);
    bool vC = seC.x < seC.y;
    if (vC) rcC = rec[seC.x];

#pragma unroll 1
    for (int rep = 0; rep < REPS; rep++) {
      bool vN = (rep + 1 < REPS) && (seN.x < seN.y);
      float4 rcN = make_float4(0.f, 0.f, 0.f, 0.f);
      if (vN) rcN = rec[seN.x];
      int2 seNN = (rep + 2 < REPS) ? sdesc[slotbase + (rep + 2) * NPW] : seN;

      float a0 = 0.f;
      if (vC) {
        float4 r = rcC;
        int e = seC.x + 1;
        while (true) {
          bool more = e < seC.y;
          float4 rn = r;
          if (more) rn = rec[e];
          int src = __float_as_int(r.x);
          float f0 = (k & 1) ? r.y : 1.f - r.y;
          float f1 = (k & 2) ? r.z : 1.f - r.z;
          float f2 = (k & 4) ? r.w : 1.f - r.w;
          a0 = fmaf(f0 * f1 * f2, X[src], a0);
          if (!more) break;
          r = rn;
          e++;
        }
      }

      const int sl = wave * (REPS * NPW) + rep * NPW + ns;
      sAgg[sl * ROWF + k] = a0;

      seC = seN;
      seN = seNN;
      vC = vN;
      rcC = rcN;
    }
  }
  __syncthreads();

  // ---------------- phase 2 ----------------
  float4 acc = make_float4(0.f, 0.f, 0.f, 0.f);
  const float4* W4 = reinterpret_cast<const float4*>(W);
  const float* arow = &sAgg[node_l * ROWF];

  if constexpr (CIN == 1) {
#pragma unroll
    for (int kk = 0; kk < 8; kk++) {
      float a = arow[kk];
      float4 w = W4[kk * TPN + co4];
      acc.x = fmaf(a, w.x, acc.x);
      acc.y = fmaf(a, w.y, acc.y);
      acc.z = fmaf(a, w.z, acc.z);
      acc.w = fmaf(a, w.w, acc.w);
    }
  } else {
    constexpr int Q = CIN / 4;
    const int swz = node_l & 7;
#pragma unroll 2
    for (int kk = 0; kk < 8; kk++) {
#pragma unroll
      for (int c = 0; c < Q; c++) {
        float4 a4 = *reinterpret_cast<const float4*>(
            &arow[((kk * Q + c) ^ swz) * 4]);
        float4 w0 = W4[(kk * CIN + 4 * c + 0) * TPN + co4];
        float4 w1 = W4[(kk * CIN + 4 * c + 1) * TPN + co4];
        float4 w2 = W4[(kk * CIN + 4 * c + 2) * TPN + co4];
        float4 w3 = W4[(kk * CIN + 4 * c + 3) * TPN + co4];
        acc.x = fmaf(a4.x, w0.x, acc.x);
        acc.y = fmaf(a4.x, w0.y, acc.y);
        acc.z = fmaf(a4.x, w0.z, acc.z);
        acc.w = fmaf(a4.x, w0.w, acc.w);
        acc.x = fmaf(a4.y, w1.x, acc.x);
        acc.y = fmaf(a4.y, w1.y, acc.y);
        acc.z = fmaf(a4.y, w1.z, acc.z);
        acc.w = fmaf(a4.y, w1.w, acc.w);
        acc.x = fmaf(a4.z, w2.x, acc.x);
        acc.y = fmaf(a4.z, w2.y, acc.y);
        acc.z = fmaf(a4.z, w2.z, acc.z);
        acc.w = fmaf(a4.z, w2.w, acc.w);
        acc.x = fmaf(a4.w, w3.x, acc.x);
        acc.y = fmaf(a4.w, w3.y, acc.y);
        acc.z = fmaf(a4.w, w3.z, acc.z);
        acc.w = fmaf(a4.w, w3.w, acc.w);
      }
    }
  }

  float v[4] = {acc.x, acc.y, acc.z, acc.w};
#pragma unroll
  for (int i = 0; i < 4; i++) {
    float w = v[i] * rc;
    v[i] = w > 0.f ? w : expm1f(w);
  }
  if constexpr (RES) {
    v[0] += rres.x;
    v[1] += rres.y;
    v[2] += rres.z;
    v[3] += rres.w;
  }

  if constexpr (POOL) {
    int cx = (int)floorf(p0 / 16.0f);
    int cy = (int)floorf(p1 / 12.0f);
    int cl = bi * G + cy * GX + cx;
    float* pr = pooled + cl * 32 + co4 * 4;
#pragma unroll
    for (int i = 0; i < 4; i++) atomicMaxFloat(&pr[i], v[i]);
  } else {
    *reinterpret_cast<float4*>(Y + (size_t)n2 * COUT + co4 * 4) =
        make_float4(v[0], v[1], v[2], v[3]);
  }
}

// ================= final FC =================
__global__ __launch_bounds__(256) void fc_kernel(const float* __restrict__ pooled,
                                                 const float* __restrict__ fcw,
                                                 float* __restrict__ out) {
  int b = blockIdx.x >> 1;
  int o = blockIdx.x & 1;
  const float* pb = pooled + b * (G * 32);
  float s = 0.f;
  for (int i = threadIdx.x; i < G * 32; i += 256) {
    float v = pb[i];
    v = isfinite(v) ? v : 0.f;  // untouched cells (0xFF memset -> NaN) -> 0
    s += v * fcw[i * 2 + o];
  }
  __shared__ float red[256];
  red[threadIdx.x] = s;
  __syncthreads();
  for (int st = 128; st > 0; st >>= 1) {
    if (threadIdx.x < st) red[threadIdx.x] += red[threadIdx.x + st];
    __syncthreads();
  }
  if (threadIdx.x == 0) out[b * 2 + o] = red[0];
}

extern "C" void kernel_launch(void* const* d_in, const int* in_sizes, int n_in,
                              void* d_out, int out_size, void* d_ws, size_t ws_size,
                              hipStream_t stream) {
  const float* x     = (const float*)d_in[0];
  const float* pos   = (const float*)d_in[1];
  const float* ea    = (const float*)d_in[2];
  const int*   ei    = (const int*)d_in[3];
  const int*   batch = (const int*)d_in[4];
  const float* fcw   = (const float*)d_in[5];
  const float* w1    = (const float*)d_in[6];
  const float* w2    = (const float*)d_in[7];
  const float* w3    = (const float*)d_in[8];
  const float* w4    = (const float*)d_in[9];
  const float* w5    = (const float*)d_in[10];
  const float* w6    = (const float*)d_in[11];
  const float* w7    = (const float*)d_in[12];
  float* out = (float*)d_out;

  // ---- workspace layout (256B-aligned chunks) ----
  char* ws = (char*)d_ws;
  size_t off = 0;
  auto alloc = [&](size_t bytes) {
    size_t p = off;
    off += (bytes + 255) & ~(size_t)255;
    return ws + p;
  };
  float*  rcnt   = (float*)alloc((size_t)N * 4);
  int*    cnt    = (int*)alloc((size_t)N * 4);
  int*    rowptr = (int*)alloc((size_t)(N + 1) * 4);
  int*    cursor = (int*)alloc((size_t)N * 4);
  int*    bsum   = (int*)alloc(512 * 4);
  int*    boff   = (int*)alloc(512 * 4);
  int*    bh     = (int*)alloc((size_t)64 * NB * 4);
  int*    order  = (int*)alloc((size_t)N * 4);
  int2*   sdesc  = (int2*)alloc((size_t)N * 8);
  float4* rec    = (float4*)alloc((size_t)E * 16);
  float*  bufA   = (float*)alloc((size_t)N * 32 * 4);
  float*  bufB   = (float*)alloc((size_t)N * 32 * 4);
  float*  bufC   = (float*)alloc((size_t)N * 32 * 4);
  float*  pooled = (float*)alloc((size_t)B_ * G * 32 * 4);

  // ---- CSR build ----
  hipMemsetAsync(cnt, 0, (size_t)N * 4, stream);
  count_kernel<<<EB, 256, 0, stream>>>(ei, cnt);
  rcnt_kernel<<<NB, 256, 0, stream>>>(cnt, rcnt);
  reduce_cnt<<<NB, 256, 0, stream>>>(cnt, bsum);
  scan_bsum<<<1, 512, 0, stream>>>(bsum, boff);
  write_rowptr<<<NB, 256, 0, stream>>>(cnt, boff, rowptr, cursor);
  edge_scatter<<<EB, 256, 0, stream>>>(ei, ea, cursor, rec);

  // ---- degree counting sort (deterministic, contention-free) ----
  block_hist<<<NB, 256, 0, stream>>>(cnt, bh);
  scan_bh<<<1, 256, 0, stream>>>(bh);
  order_block<<<NB, 256, 0, stream>>>(cnt, bh, rowptr, order, sdesc);

  // ---- pooled init (must precede conv7) ----
  hipMemsetAsync(pooled, 0xFF, (size_t)B_ * G * 32 * 4, stream);

  // ---- conv ladder (transposed-gather factored) ----
  // conv1: 1->8    x -> A        NPB=128
  node_conv_v5<1, 8, false, false><<<N / 128, 256, 0, stream>>>(
      x, w1, rec, sdesc, order, rcnt, nullptr, bufA, nullptr, nullptr, nullptr);
  // conv2: 8->16   A -> B   (B = h_sc1)   NPB=64
  node_conv_v5<8, 16, false, false><<<N / 64, 256, 0, stream>>>(
      bufA, w2, rec, sdesc, order, rcnt, nullptr, bufB, nullptr, nullptr, nullptr);
  // conv3: 16->16  B -> C
  node_conv_v5<16, 16, false, false><<<N / 64, 256, 0, stream>>>(
      bufB, w3, rec, sdesc, order, rcnt, nullptr, bufC, nullptr, nullptr, nullptr);
  // conv4: 16->16  C -> A, + residual B
  node_conv_v5<16, 16, true, false><<<N / 64, 256, 0, stream>>>(
      bufC, w4, rec, sdesc, order, rcnt, bufB, bufA, nullptr, nullptr, nullptr);
  // conv5: 16->32  A -> C   (C = h_sc2)   NPB=32
  node_conv_v5<16, 32, false, false><<<N / 32, 256, 0, stream>>>(
      bufA, w5, rec, sdesc, order, rcnt, nullptr, bufC, nullptr, nullptr, nullptr);
  // conv6: 32->32  C -> B
  node_conv_v5<32, 32, false, false><<<N / 32, 256, 0, stream>>>(
      bufC, w6, rec, sdesc, order, rcnt, nullptr, bufB, nullptr, nullptr, nullptr);
  // conv7: 32->32  B -> (pool), + residual C
  node_conv_v5<32, 32, true, true><<<N / 32, 256, 0, stream>>>(
      bufB, w7, rec, sdesc, order, rcnt, bufC, nullptr, pos, batch, pooled);

  // ---- FC ----
  fc_kernel<<<B_ * 2, 256, 0, stream>>>(pooled, fcw, out);
}

// Round 11
// 635.927 us; speedup vs baseline: 12.5886x; 1.0990x over previous
//
#include <hip/hip_runtime.h>
#include <math.h>

// ---- static problem config (matches reference) ----
namespace {
constexpr int N  = 102400;   // nodes
constexpr int E  = 819200;   // edges
constexpr int B_ = 16;       // graphs
constexpr int G  = 72;       // voxel cells per graph (8 x 9)
constexpr int GX = 8;
constexpr int NB = N / 256;  // 400 blocks over nodes
constexpr int EB = E / 256;  // 3200 blocks over edges
}

// ================= CSR build =================

__global__ __launch_bounds__(256) void count_kernel(const int* __restrict__ ei,
                                                    int* __restrict__ cnt) {
  int e = blockIdx.x * 256 + threadIdx.x;
  atomicAdd(&cnt[ei[E + e]], 1);
}

__global__ __launch_bounds__(256) void rcnt_kernel(const int* __restrict__ cnt,
                                                   float* __restrict__ rcnt) {
  int n = blockIdx.x * 256 + threadIdx.x;
  rcnt[n] = 1.0f / (float)max(cnt[n], 1);
}

// per-256-chunk sums of cnt
__global__ __launch_bounds__(256) void reduce_cnt(const int* __restrict__ cnt,
                                                  int* __restrict__ bsum) {
  __shared__ int s[256];
  int i = blockIdx.x * 256 + threadIdx.x;
  s[threadIdx.x] = cnt[i];
  __syncthreads();
  for (int st = 128; st > 0; st >>= 1) {
    if (threadIdx.x < st) s[threadIdx.x] += s[threadIdx.x + st];
    __syncthreads();
  }
  if (threadIdx.x == 0) bsum[blockIdx.x] = s[0];
}

// single-block exclusive scan of the NB block sums
__global__ __launch_bounds__(512) void scan_bsum(const int* __restrict__ bsum,
                                                 int* __restrict__ boff) {
  __shared__ int s[512];
  int i = threadIdx.x;
  int v = (i < NB) ? bsum[i] : 0;
  s[i] = v;
  __syncthreads();
  for (int st = 1; st < 512; st <<= 1) {
    int t = (i >= st) ? s[i - st] : 0;
    __syncthreads();
    s[i] += t;
    __syncthreads();
  }
  if (i < NB) boff[i] = s[i] - v;  // exclusive
}

// rowptr[n] = exclusive scan of cnt; cursor = rowptr; sdesc[n] = (beg, end)
__global__ __launch_bounds__(256) void write_rowptr(const int* __restrict__ cnt,
                                                    const int* __restrict__ boff,
                                                    int* __restrict__ rowptr,
                                                    int* __restrict__ cursor,
                                                    int2* __restrict__ sdesc) {
  __shared__ int s[256];
  int i = blockIdx.x * 256 + threadIdx.x;
  int v = cnt[i];
  s[threadIdx.x] = v;
  __syncthreads();
  for (int st = 1; st < 256; st <<= 1) {
    int t = (threadIdx.x >= st) ? s[threadIdx.x - st] : 0;
    __syncthreads();
    s[threadIdx.x] += t;
    __syncthreads();
  }
  int off = boff[blockIdx.x] + s[threadIdx.x] - v;  // exclusive
  rowptr[i] = off;
  cursor[i] = off;
  sdesc[i] = make_int2(off, off + v);
  if (i == N - 1) rowptr[N] = off + v;
}

// scatter edge records (src + clamped pseudo-coords) into CSR order
__global__ __launch_bounds__(256) void edge_scatter(const int* __restrict__ ei,
                                                    const float* __restrict__ ea,
                                                    int* __restrict__ cursor,
                                                    float4* __restrict__ rec) {
  int e = blockIdx.x * 256 + threadIdx.x;
  int src = ei[e];
  int dst = ei[E + e];
  float u0 = fminf(fmaxf(ea[3 * e + 0], 0.f), 1.f);
  float u1 = fminf(fmaxf(ea[3 * e + 1], 0.f), 1.f);
  float u2 = fminf(fmaxf(ea[3 * e + 2], 0.f), 1.f);
  int slot = atomicAdd(&cursor[dst], 1);
  rec[slot] = make_float4(__int_as_float(src), u0, u1, u2);
}

// ================= pooling helper =================
__device__ __forceinline__ void atomicMaxFloat(float* addr, float val) {
  if (val >= 0.f)
    atomicMax(reinterpret_cast<int*>(addr), __float_as_int(val));
  else
    atomicMin(reinterpret_cast<unsigned int*>(addr), __float_as_uint(val));
}

// ====== LDS-bridged factored spline conv (v6: graph-local, XCD-swizzled) ======
// out[n] = (1/deg) * sum_k ( sum_{e->n} b_k(e) * x_src(e) ) @ W[k]
//
// Round-11: NO degree sort. Slots ARE node indices (graph-contiguous). The
// 2-edge-deep pipeline makes deg<=16 fixed-cost, so degree uniformity is moot
// (P(deg>16) ~ 0.4% takes the fallback loop). Block index is XCD-swizzled:
//   sb = (blockIdx%8)*(grid/8) + blockIdx/8
// so each XCD (round-robin dispatch) owns a contiguous node range = 2 graphs
// -> per-XCD X working set 1.6 MB fits its 4 MB L2 -> x-gathers L2-hit
// (round-10 FETCH showed E*128B = zero L2 reuse without this).
// Epilogue reads + Y writes are now fully coalesced (identity order).
template <int CIN, int COUT, bool RES, bool POOL>
__global__ __launch_bounds__(256, 4) void node_conv_v6(
    const float* __restrict__ X, const float* __restrict__ W,
    const float4* __restrict__ rec, const int2* __restrict__ sdesc,
    const float* __restrict__ rcnt, const float* __restrict__ res,
    float* __restrict__ Y, const float* __restrict__ pos,
    const int* __restrict__ batch, float* __restrict__ pooled) {
  constexpr int TPN  = COUT / 4;                    // phase-2 threads per node
  constexpr int NPB  = 256 / TPN;                   // nodes per block
  constexpr int ROWF = (CIN >= 8) ? 8 * CIN : 12;   // LDS floats per node row

  __shared__ float sAgg[NPB * ROWF];

  const int tid  = threadIdx.x;
  const int wave = tid >> 6;
  const int lane = tid & 63;

  // XCD swizzle: consecutive node chunks land on one XCD
  const int sb = (blockIdx.x & 7) * (gridDim.x >> 3) + (blockIdx.x >> 3);
  const int nbase = sb * NPB;

  // ---- phase-2 epilogue gathers hoisted to top (coalesced now) ----
  const int node_l = tid / TPN;
  const int co4 = tid % TPN;
  const int n2 = nbase + node_l;
  const float rc = rcnt[n2];
  float4 rres = make_float4(0.f, 0.f, 0.f, 0.f);
  if constexpr (RES)
    rres = *reinterpret_cast<const float4*>(res + (size_t)n2 * COUT + co4 * 4);
  float p0 = 0.f, p1 = 0.f;
  int bi = 0;
  if constexpr (POOL) {
    p0 = pos[n2 * 3 + 0];
    p1 = pos[n2 * 3 + 1];
    bi = batch[n2];
  }

  // ---------------- phase 1 ----------------
  if constexpr (CIN >= 8) {
    constexpr int QN   = CIN / 4;          // channel quads per row
    constexpr int LPN  = 8 * QN;           // lanes per node
    constexpr int NPW  = 64 / LPN;         // nodes per wave per rep
    constexpr int REPS = NPB / (4 * NPW);  // reps per wave

    const int ci4  = lane % QN;
    const int esub = (lane / QN) & 7;
    const int ns   = lane / LPN;
    const int kstar = ((lane / QN) & 1) * 4 + ((lane / (2 * QN)) & 1) * 2 +
                      ((lane / (4 * QN)) & 1);
    const int slot0 = wave * (REPS * NPW) + ns;  // local slot of rep 0

    auto loadDesc = [&](int rep) -> int2 {
      int r = min(rep, REPS - 1);
      return sdesc[nbase + slot0 + r * NPW];
    };
    auto loadRec = [&](int e) -> float4 { return rec[min(e, E - 1)]; };
    auto loadX = [&](const float4& r) -> float4 {
      int src = __float_as_int(r.x);
      return *(reinterpret_cast<const float4*>(X + (size_t)src * CIN) + ci4);
    };

    // pipeline prologue
    int2 d0 = loadDesc(0);
    int2 d1 = loadDesc(1);
    int2 d2 = loadDesc(2);
    float4 ra0 = loadRec(d0.x + esub), rb0 = loadRec(d0.x + esub + 8);
    float4 ra1 = loadRec(d1.x + esub), rb1 = loadRec(d1.x + esub + 8);
    float4 xa0 = loadX(ra0), xb0 = loadX(rb0);

#pragma unroll 1
    for (int rep = 0; rep < REPS; rep++) {
      // issue next-rep x pair (recs arrived one rep ago)
      float4 xa1 = loadX(ra1), xb1 = loadX(rb1);
      // issue rep+2 rec pair (desc arrived one rep ago)
      float4 ra2 = loadRec(d2.x + esub), rb2 = loadRec(d2.x + esub + 8);
      // issue rep+3 desc
      int2 d3 = loadDesc(rep + 3);

      float agg[32];
#pragma unroll
      for (int i = 0; i < 32; i++) agg[i] = 0.f;

      auto accum = [&](const float4& r, const float4& v, bool valid) {
        float uy = r.y, uz = r.z, uw = r.w;
        float py = 1.f - uy, pz = 1.f - uz, pw = 1.f - uw;
        float g = valid ? 1.f : 0.f;
        float t0 = py * pz * g, t1 = uy * pz * g;
        float t2 = py * uz * g, t3 = uy * uz * g;
        float b[8] = {t0 * pw, t1 * pw, t2 * pw, t3 * pw,
                      t0 * uw, t1 * uw, t2 * uw, t3 * uw};
#pragma unroll
        for (int k = 0; k < 8; k++) {
          agg[k * 4 + 0] = fmaf(b[k], v.x, agg[k * 4 + 0]);
          agg[k * 4 + 1] = fmaf(b[k], v.y, agg[k * 4 + 1]);
          agg[k * 4 + 2] = fmaf(b[k], v.z, agg[k * 4 + 2]);
          agg[k * 4 + 3] = fmaf(b[k], v.w, agg[k * 4 + 3]);
        }
      };

      accum(ra0, xa0, d0.x + esub < d0.y);
      accum(rb0, xb0, d0.x + esub + 8 < d0.y);
      // rare: deg > 16 (P ~ 0.4%), exposed-latency fallback
#pragma unroll 1
      for (int e = d0.x + esub + 16; e < d0.y; e += 8) {
        float4 rr = rec[e];
        float4 xx = loadX(rr);
        accum(rr, xx, true);
      }

      // reduce-and-split over esub bits; payload 32 -> 16 -> 8 -> 4
#pragma unroll
      for (int s = 0; s < 3; s++) {
        const int m = QN << s;
        const int H = 16 >> s;
        bool up = (lane & m) != 0;
#pragma unroll
        for (int i = 0; i < H; i++) {
          float keep = up ? agg[i + H] : agg[i];
          float send = up ? agg[i] : agg[i + H];
          agg[i] = keep + __shfl_xor(send, m, 64);
        }
      }

      const int sl = slot0 + rep * NPW;
      const int idx4 = (kstar * QN + ci4) ^ (sl & 7);  // block swizzle
      *reinterpret_cast<float4*>(&sAgg[sl * ROWF + idx4 * 4]) =
          make_float4(agg[0], agg[1], agg[2], agg[3]);

      // rotate pipeline
      d0 = d1; d1 = d2; d2 = d3;
      ra0 = ra1; rb0 = rb1; ra1 = ra2; rb1 = rb2;
      xa0 = xa1; xb0 = xb1;
    }
  } else {
    // CIN == 1: lane = (node_sub, k); serial edge walk with prefetch
    constexpr int LPN  = 8;
    constexpr int NPW  = 8;
    constexpr int REPS = NPB / (4 * NPW);
    const int ns = lane / LPN;
    const int k  = lane & 7;
    const int slotbase = nbase + wave * (REPS * NPW) + ns;

    int2 seC = sdesc[slotbase];
    int2 seN = (REPS > 1) ? sdesc[slotbase + NPW] : seC;
    float4 rcC = make_float4(0.f, 0.f, 0.f, 0.f);
    bool vC = seC.x < seC.y;
    if (vC) rcC = rec[seC.x];

#pragma unroll 1
    for (int rep = 0; rep < REPS; rep++) {
      bool vN = (rep + 1 < REPS) && (seN.x < seN.y);
      float4 rcN = make_float4(0.f, 0.f, 0.f, 0.f);
      if (vN) rcN = rec[seN.x];
      int2 seNN = (rep + 2 < REPS) ? sdesc[slotbase + (rep + 2) * NPW] : seN;

      float a0 = 0.f;
      if (vC) {
        float4 r = rcC;
        int e = seC.x + 1;
        while (true) {
          bool more = e < seC.y;
          float4 rn = r;
          if (more) rn = rec[e];
          int src = __float_as_int(r.x);
          float f0 = (k & 1) ? r.y : 1.f - r.y;
          float f1 = (k & 2) ? r.z : 1.f - r.z;
          float f2 = (k & 4) ? r.w : 1.f - r.w;
          a0 = fmaf(f0 * f1 * f2, X[src], a0);
          if (!more) break;
          r = rn;
          e++;
        }
      }

      const int sl = wave * (REPS * NPW) + rep * NPW + ns;
      sAgg[sl * ROWF + k] = a0;

      seC = seN;
      seN = seNN;
      vC = vN;
      rcC = rcN;
    }
  }
  __syncthreads();

  // ---------------- phase 2 ----------------
  float4 acc = make_float4(0.f, 0.f, 0.f, 0.f);
  const float4* W4 = reinterpret_cast<const float4*>(W);
  const float* arow = &sAgg[node_l * ROWF];

  if constexpr (CIN == 1) {
#pragma unroll
    for (int kk = 0; kk < 8; kk++) {
      float a = arow[kk];
      float4 w = W4[kk * TPN + co4];
      acc.x = fmaf(a, w.x, acc.x);
      acc.y = fmaf(a, w.y, acc.y);
      acc.z = fmaf(a, w.z, acc.z);
      acc.w = fmaf(a, w.w, acc.w);
    }
  } else {
    constexpr int Q = CIN / 4;
    const int swz = node_l & 7;
#pragma unroll 2
    for (int kk = 0; kk < 8; kk++) {
#pragma unroll
      for (int c = 0; c < Q; c++) {
        float4 a4 = *reinterpret_cast<const float4*>(
            &arow[((kk * Q + c) ^ swz) * 4]);
        float4 w0 = W4[(kk * CIN + 4 * c + 0) * TPN + co4];
        float4 w1 = W4[(kk * CIN + 4 * c + 1) * TPN + co4];
        float4 w2 = W4[(kk * CIN + 4 * c + 2) * TPN + co4];
        float4 w3 = W4[(kk * CIN + 4 * c + 3) * TPN + co4];
        acc.x = fmaf(a4.x, w0.x, acc.x);
        acc.y = fmaf(a4.x, w0.y, acc.y);
        acc.z = fmaf(a4.x, w0.z, acc.z);
        acc.w = fmaf(a4.x, w0.w, acc.w);
        acc.x = fmaf(a4.y, w1.x, acc.x);
        acc.y = fmaf(a4.y, w1.y, acc.y);
        acc.z = fmaf(a4.y, w1.z, acc.z);
        acc.w = fmaf(a4.y, w1.w, acc.w);
        acc.x = fmaf(a4.z, w2.x, acc.x);
        acc.y = fmaf(a4.z, w2.y, acc.y);
        acc.z = fmaf(a4.z, w2.z, acc.z);
        acc.w = fmaf(a4.z, w2.w, acc.w);
        acc.x = fmaf(a4.w, w3.x, acc.x);
        acc.y = fmaf(a4.w, w3.y, acc.y);
        acc.z = fmaf(a4.w, w3.z, acc.z);
        acc.w = fmaf(a4.w, w3.w, acc.w);
      }
    }
  }

  float v[4] = {acc.x, acc.y, acc.z, acc.w};
#pragma unroll
  for (int i = 0; i < 4; i++) {
    float w = v[i] * rc;
    v[i] = w > 0.f ? w : expm1f(w);
  }
  if constexpr (RES) {
    v[0] += rres.x;
    v[1] += rres.y;
    v[2] += rres.z;
    v[3] += rres.w;
  }

  if constexpr (POOL) {
    int cx = (int)floorf(p0 / 16.0f);
    int cy = (int)floorf(p1 / 12.0f);
    int cl = bi * G + cy * GX + cx;
    float* pr = pooled + cl * 32 + co4 * 4;
#pragma unroll
    for (int i = 0; i < 4; i++) atomicMaxFloat(&pr[i], v[i]);
  } else {
    *reinterpret_cast<float4*>(Y + (size_t)n2 * COUT + co4 * 4) =
        make_float4(v[0], v[1], v[2], v[3]);
  }
}

// ================= final FC =================
__global__ __launch_bounds__(256) void fc_kernel(const float* __restrict__ pooled,
                                                 const float* __restrict__ fcw,
                                                 float* __restrict__ out) {
  int b = blockIdx.x >> 1;
  int o = blockIdx.x & 1;
  const float* pb = pooled + b * (G * 32);
  float s = 0.f;
  for (int i = threadIdx.x; i < G * 32; i += 256) {
    float v = pb[i];
    v = isfinite(v) ? v : 0.f;  // untouched cells (0xFF memset -> NaN) -> 0
    s += v * fcw[i * 2 + o];
  }
  __shared__ float red[256];
  red[threadIdx.x] = s;
  __syncthreads();
  for (int st = 128; st > 0; st >>= 1) {
    if (threadIdx.x < st) red[threadIdx.x] += red[threadIdx.x + st];
    __syncthreads();
  }
  if (threadIdx.x == 0) out[b * 2 + o] = red[0];
}

extern "C" void kernel_launch(void* const* d_in, const int* in_sizes, int n_in,
                              void* d_out, int out_size, void* d_ws, size_t ws_size,
                              hipStream_t stream) {
  const float* x     = (const float*)d_in[0];
  const float* pos   = (const float*)d_in[1];
  const float* ea    = (const float*)d_in[2];
  const int*   ei    = (const int*)d_in[3];
  const int*   batch = (const int*)d_in[4];
  const float* fcw   = (const float*)d_in[5];
  const float* w1    = (const float*)d_in[6];
  const float* w2    = (const float*)d_in[7];
  const float* w3    = (const float*)d_in[8];
  const float* w4    = (const float*)d_in[9];
  const float* w5    = (const float*)d_in[10];
  const float* w6    = (const float*)d_in[11];
  const float* w7    = (const float*)d_in[12];
  float* out = (float*)d_out;

  // ---- workspace layout (256B-aligned chunks) ----
  char* ws = (char*)d_ws;
  size_t off = 0;
  auto alloc = [&](size_t bytes) {
    size_t p = off;
    off += (bytes + 255) & ~(size_t)255;
    return ws + p;
  };
  float*  rcnt   = (float*)alloc((size_t)N * 4);
  int*    cnt    = (int*)alloc((size_t)N * 4);
  int*    rowptr = (int*)alloc((size_t)(N + 1) * 4);
  int*    cursor = (int*)alloc((size_t)N * 4);
  int*    bsum   = (int*)alloc(512 * 4);
  int*    boff   = (int*)alloc(512 * 4);
  int2*   sdesc  = (int2*)alloc((size_t)N * 8);
  float4* rec    = (float4*)alloc((size_t)E * 16);
  float*  bufA   = (float*)alloc((size_t)N * 32 * 4);
  float*  bufB   = (float*)alloc((size_t)N * 32 * 4);
  float*  bufC   = (float*)alloc((size_t)N * 32 * 4);
  float*  pooled = (float*)alloc((size_t)B_ * G * 32 * 4);

  // ---- CSR build ----
  hipMemsetAsync(cnt, 0, (size_t)N * 4, stream);
  count_kernel<<<EB, 256, 0, stream>>>(ei, cnt);
  rcnt_kernel<<<NB, 256, 0, stream>>>(cnt, rcnt);
  reduce_cnt<<<NB, 256, 0, stream>>>(cnt, bsum);
  scan_bsum<<<1, 512, 0, stream>>>(bsum, boff);
  write_rowptr<<<NB, 256, 0, stream>>>(cnt, boff, rowptr, cursor, sdesc);
  edge_scatter<<<EB, 256, 0, stream>>>(ei, ea, cursor, rec);

  // ---- pooled init (must precede conv7) ----
  hipMemsetAsync(pooled, 0xFF, (size_t)B_ * G * 32 * 4, stream);

  // ---- conv ladder (graph-local, XCD-swizzled) ----
  // conv1: 1->8    x -> A        NPB=128
  node_conv_v6<1, 8, false, false><<<N / 128, 256, 0, stream>>>(
      x, w1, rec, sdesc, rcnt, nullptr, bufA, nullptr, nullptr, nullptr);
  // conv2: 8->16   A -> B   (B = h_sc1)   NPB=64
  node_conv_v6<8, 16, false, false><<<N / 64, 256, 0, stream>>>(
      bufA, w2, rec, sdesc, rcnt, nullptr, bufB, nullptr, nullptr, nullptr);
  // conv3: 16->16  B -> C
  node_conv_v6<16, 16, false, false><<<N / 64, 256, 0, stream>>>(
      bufB, w3, rec, sdesc, rcnt, nullptr, bufC, nullptr, nullptr, nullptr);
  // conv4: 16->16  C -> A, + residual B
  node_conv_v6<16, 16, true, false><<<N / 64, 256, 0, stream>>>(
      bufC, w4, rec, sdesc, rcnt, bufB, bufA, nullptr, nullptr, nullptr);
  // conv5: 16->32  A -> C   (C = h_sc2)   NPB=32
  node_conv_v6<16, 32, false, false><<<N / 32, 256, 0, stream>>>(
      bufA, w5, rec, sdesc, rcnt, nullptr, bufC, nullptr, nullptr, nullptr);
  // conv6: 32->32  C -> B
  node_conv_v6<32, 32, false, false><<<N / 32, 256, 0, stream>>>(
      bufC, w6, rec, sdesc, rcnt, nullptr, bufB, nullptr, nullptr, nullptr);
  // conv7: 32->32  B -> (pool), + residual C
  node_conv_v6<32, 32, true, true><<<N / 32, 256, 0, stream>>>(
      bufB, w7, rec, sdesc, rcnt, bufC, nullptr, pos, batch, pooled);

  // ---- FC ----
  fc_kernel<<<B_ * 2, 256, 0, stream>>>(pooled, fcw, out);
}